// Round 11
// baseline (1136.888 us; speedup 1.0000x reference)
//
#include <hip/hip_runtime.h>
#include <hip/hip_bf16.h>
#include <math.h>

#define NHEAD 12
#define CDIM 384
#define QKVC 1152
#define MLPH 1536
#define SCALE 0.17677669529663687f  // 32^-0.5

typedef __attribute__((ext_vector_type(8))) short short8;
typedef __attribute__((ext_vector_type(4))) float f32x4;

static __device__ __forceinline__ unsigned short f2bf(float f) {
  union { __hip_bfloat16 b; unsigned short u; } c;
  c.b = __float2bfloat16(f);
  return c.u;
}

// fast GELU (tanh form), NaN-safe; |err| vs exact erf-GELU < ~2e-4
static __device__ __forceinline__ float gelu_f(float x) {
  float x3 = x * x * x;
  float y = 0.7978845608028654f * (x + 0.044715f * x3);
  float e = __expf(2.f * y);
  float th = 1.f - 2.f / (e + 1.f);
  return 0.5f * x * (1.f + th);
}

// ---------------- LN (wave per token, C=384) -> bf16 out ----------------
__global__ void ln_kernel(const float* __restrict__ X, const float* __restrict__ g,
                          const float* __restrict__ b, __hip_bfloat16* __restrict__ Y, int T) {
  int wid = (blockIdx.x * blockDim.x + threadIdx.x) >> 6;
  int lane = threadIdx.x & 63;
  if (wid >= T) return;
  const float* x = X + (size_t)wid * CDIM;
  float vals[6];
  float s = 0.f;
#pragma unroll
  for (int i = 0; i < 6; i++) { vals[i] = x[lane + i * 64]; s += vals[i]; }
#pragma unroll
  for (int o = 32; o > 0; o >>= 1) s += __shfl_xor(s, o);
  float m = s * (1.f / 384.f);
  float vs = 0.f;
#pragma unroll
  for (int i = 0; i < 6; i++) { float d = vals[i] - m; vs += d * d; }
#pragma unroll
  for (int o = 32; o > 0; o >>= 1) vs += __shfl_xor(vs, o);
  float rs = rsqrtf(vs * (1.f / 384.f) + 1e-5f);
  __hip_bfloat16* y = Y + (size_t)wid * CDIM;
#pragma unroll
  for (int i = 0; i < 6; i++) {
    int c = lane + i * 64;
    y[c] = __float2bfloat16((vals[i] - m) * rs * g[c] + b[c]);
  }
}

// ------------- qkv of a padded (zero) token: ln1_b @ qkv_w + qkv_b -> bf16 -------------
__global__ void pad_qkv_kernel(const float* __restrict__ lb, const float* __restrict__ Wq,
                               const float* __restrict__ bq, __hip_bfloat16* __restrict__ outp) {
  int j = blockIdx.x * blockDim.x + threadIdx.x;
  if (j >= QKVC) return;
  float s = bq[j];
  for (int c = 0; c < CDIM; c++) s += lb[c] * Wq[(size_t)c * QKVC + j];
  outp[j] = __float2bfloat16(s);
}

// ------------- expand relative-position bias to padded [12][64][64] f32 -------------
__global__ void expand_bias(const float* __restrict__ biases, const int* __restrict__ bidx,
                            float* __restrict__ Bexp, int n_off) {
  int h = blockIdx.x;
  for (int e = threadIdx.x; e < 4096; e += 256) {
    int n = e >> 6, m = e & 63;
    float v;
    if (m >= 49) v = -1e30f;
    else if (n >= 49) v = 0.f;
    else v = biases[h * n_off + bidx[n * 49 + m]];
    Bexp[h * 4096 + e] = v;
  }
}

// ---------------- weight transpose + f32->bf16 convert: W[K][N] -> Wt[N][K] ----------------
__global__ void wt_convert(const float* __restrict__ W, __hip_bfloat16* __restrict__ Wt,
                           int K, int N) {
  __shared__ float t[32][33];
  int n0 = blockIdx.x * 32, k0 = blockIdx.y * 32;
  int tx = threadIdx.x, ty = threadIdx.y;  // 32 x 8
#pragma unroll
  for (int i = 0; i < 4; i++) t[ty + i * 8][tx] = W[(size_t)(k0 + ty + i * 8) * N + n0 + tx];
  __syncthreads();
#pragma unroll
  for (int i = 0; i < 4; i++)
    Wt[(size_t)(n0 + ty + i * 8) * K + k0 + tx] = __float2bfloat16(t[tx][ty + i * 8]);
}

// -------- pack fc1_w [384][1536] into phase-1 MFMA fragment order --------
// frag f = ks*96 + kk*8 + g (g = 16-wide h-group); lane holds B[n][k]:
// n = ks*128 + g*16 + (lane&15), k = kk*32 + (lane>>4)*8 + j
__global__ void wfrag1(const float* __restrict__ W, unsigned short* __restrict__ WF) {
  int f = blockIdx.x;
  int lane = threadIdx.x;
  int g = f & 7, kk = (f >> 3) % 12, ks = f / 96;
  int n = ks * 128 + g * 16 + (lane & 15);
  int k = kk * 32 + (lane >> 4) * 8;
  unsigned short* dst = WF + ((size_t)f * 64 + lane) * 8;
#pragma unroll
  for (int j = 0; j < 8; j++) dst[j] = f2bf(W[(size_t)(k + j) * MLPH + n]);
}

// -------- pack fc2_w [1536][384] into phase-2 MFMA fragment order --------
// frag f = ks*96 + kk*24 + g2 (g2 = 16-wide n-group); lane holds B[n][k]:
// n = g2*16 + (lane&15), k = ks*128 + kk*32 + (lane>>4)*8 + jj
__global__ void wfrag2(const float* __restrict__ W, unsigned short* __restrict__ WF) {
  int f = blockIdx.x;
  int lane = threadIdx.x;
  int g2 = f % 24, kk = (f / 24) & 3, ks = f / 96;
  int n = g2 * 16 + (lane & 15);
  int k = ks * 128 + kk * 32 + (lane >> 4) * 8;
  unsigned short* dst = WF + ((size_t)f * 64 + lane) * 8;
#pragma unroll
  for (int jj = 0; jj < 8; jj++) dst[jj] = f2bf(W[(size_t)(k + jj) * CDIM + n]);
}

// ---------------- bf16 MFMA GEMM (R4 form): C = A @ Bt^T + bias (+res) ----------------
template <int GELU, int HAS_RES, int OUT_BF16>
__global__ __launch_bounds__(256) void gemm_mfma(
    const __hip_bfloat16* __restrict__ A, const __hip_bfloat16* __restrict__ Bt,
    const float* __restrict__ bias, const float* __restrict__ res,
    void* __restrict__ Cout, int M, int N, int K) {
  __shared__ unsigned short Al[128][72];
  __shared__ unsigned short Bl[64][72];
  int tid = threadIdx.x;
  int m0 = blockIdx.y * 128, n0 = blockIdx.x * 64;
  int wave = tid >> 6, lane = tid & 63;
  int wm = (wave >> 1) * 64, wn = (wave & 1) * 32;
  int l15 = lane & 15, l4 = lane >> 4;

  int am = tid >> 1, ak = (tid & 1) * 32;
  int bn = tid >> 2, bk = (tid & 3) * 16;
  const __hip_bfloat16* Ag = A + (size_t)(m0 + am) * K + ak;
  const __hip_bfloat16* Bg = Bt + (size_t)(n0 + bn) * K + bk;

  f32x4 acc[4][2] = {};

  for (int kt = 0; kt < K; kt += 64) {
    uint4 av0 = *(const uint4*)(Ag + kt);
    uint4 av1 = *(const uint4*)(Ag + kt + 8);
    uint4 av2 = *(const uint4*)(Ag + kt + 16);
    uint4 av3 = *(const uint4*)(Ag + kt + 24);
    uint4 bv0 = *(const uint4*)(Bg + kt);
    uint4 bv1 = *(const uint4*)(Bg + kt + 8);
    __syncthreads();
    *(uint4*)&Al[am][ak]      = av0;
    *(uint4*)&Al[am][ak + 8]  = av1;
    *(uint4*)&Al[am][ak + 16] = av2;
    *(uint4*)&Al[am][ak + 24] = av3;
    *(uint4*)&Bl[bn][bk]      = bv0;
    *(uint4*)&Bl[bn][bk + 8]  = bv1;
    __syncthreads();
#pragma unroll
    for (int kk = 0; kk < 64; kk += 32) {
      short8 af[4], bfr[2];
#pragma unroll
      for (int i = 0; i < 4; i++)
        af[i] = *(const short8*)&Al[wm + i * 16 + l15][kk + l4 * 8];
#pragma unroll
      for (int j = 0; j < 2; j++)
        bfr[j] = *(const short8*)&Bl[wn + j * 16 + l15][kk + l4 * 8];
#pragma unroll
      for (int i = 0; i < 4; i++)
#pragma unroll
        for (int j = 0; j < 2; j++)
          acc[i][j] = __builtin_amdgcn_mfma_f32_16x16x32_bf16(af[i], bfr[j], acc[i][j], 0, 0, 0);
    }
  }

#pragma unroll
  for (int i = 0; i < 4; i++) {
#pragma unroll
    for (int j = 0; j < 2; j++) {
      int n = n0 + wn + j * 16 + l15;
      float bv = bias[n];
#pragma unroll
      for (int r = 0; r < 4; r++) {
        int m = m0 + wm + i * 16 + l4 * 4 + r;
        float c = acc[i][j][r] + bv;
        if (GELU) c = gelu_f(c);
        if (HAS_RES) c += res[(size_t)m * N + n];
        if (OUT_BF16)
          ((__hip_bfloat16*)Cout)[(size_t)m * N + n] = __float2bfloat16(c);
        else
          ((float*)Cout)[(size_t)m * N + n] = c;
      }
    }
  }
}

// ---------------- fused MLP v2: OUT = gelu(XN @ W1 + b1) @ W2 + b2 + X2 ----------------
// 8 waves = 2m x 4n. Each wave holds its 24 XN A-frags in REGISTERS for the whole
// kernel (LDS A-reads: 24 once vs 48/ks). H double-buffered in LDS -> 1 barrier/ks.
__global__ __launch_bounds__(512, 2) void mlp_fused(
    const __hip_bfloat16* __restrict__ XN, const unsigned short* __restrict__ W1F,
    const float* __restrict__ B1, const unsigned short* __restrict__ W2F,
    const float* __restrict__ B2, const float* __restrict__ X2,
    float* __restrict__ OUT) {
  __shared__ unsigned short XNl[64][388];
  __shared__ unsigned short Hl[2][64][132];
  int tid = threadIdx.x;
  int m0 = blockIdx.x * 64;
  int wave = tid >> 6, lane = tid & 63;
  int wm = (wave >> 2) * 32;  // m-half: 0 / 32
  int wn = wave & 3;          // h/n quarter
  int l15 = lane & 15, l4 = lane >> 4;

  {  // stage A panel 64x384 bf16, fully coalesced
#pragma unroll
    for (int i = 0; i < 6; i++) {
      int u = tid + i * 512;
      int r = u / 48, col = (u % 48) * 8;
      *(uint4*)&XNl[r][col] =
          *(const uint4*)((const unsigned short*)XN + (size_t)(m0 + r) * 384 + col);
    }
  }
  __syncthreads();

  // A-frags to registers: af[i][kk] (i = m-16-tile within wave's half, kk = K/32)
  short8 af[2][12];
#pragma unroll
  for (int i = 0; i < 2; i++)
#pragma unroll
    for (int kk = 0; kk < 12; kk++)
      af[i][kk] = *(const short8*)&XNl[wm + i * 16 + l15][kk * 32 + l4 * 8];

  f32x4 acc[2][6] = {};

  for (int ks = 0; ks < 12; ks++) {
    int pb = ks & 1;
    // ---- phase 1: hacc[i][f] over 32 h-cols (g = wn*2+f), A from regs ----
    f32x4 hacc[2][2] = {};
    const unsigned short* w1b = W1F + ((size_t)(ks * 96 + wn * 2)) * 512 + lane * 8;
#pragma unroll
    for (int kk = 0; kk < 12; kk++) {
      short8 bf0 = *(const short8*)(w1b + kk * 4096);
      short8 bf1 = *(const short8*)(w1b + kk * 4096 + 512);
      hacc[0][0] = __builtin_amdgcn_mfma_f32_16x16x32_bf16(af[0][kk], bf0, hacc[0][0], 0, 0, 0);
      hacc[0][1] = __builtin_amdgcn_mfma_f32_16x16x32_bf16(af[0][kk], bf1, hacc[0][1], 0, 0, 0);
      hacc[1][0] = __builtin_amdgcn_mfma_f32_16x16x32_bf16(af[1][kk], bf0, hacc[1][0], 0, 0, 0);
      hacc[1][1] = __builtin_amdgcn_mfma_f32_16x16x32_bf16(af[1][kk], bf1, hacc[1][1], 0, 0, 0);
    }
    float b10 = B1[ks * 128 + wn * 32 + l15];
    float b11 = B1[ks * 128 + wn * 32 + 16 + l15];
#pragma unroll
    for (int i = 0; i < 2; i++)
#pragma unroll
      for (int f = 0; f < 2; f++) {
        float bv = f ? b11 : b10;
#pragma unroll
        for (int r = 0; r < 4; r++) {
          float c = hacc[i][f][r] + bv;
          Hl[pb][wm + i * 16 + l4 * 4 + r][wn * 32 + f * 16 + l15] = f2bf(gelu_f(c));
        }
      }
    __syncthreads();  // Hl[pb] complete; also orders WAR on Hl[pb] vs p2(ks-2)
    // ---- phase 2: acc += H(slab) @ W2 slab (wave owns 96 of 384 out-cols) ----
    const unsigned short* w2b = W2F + ((size_t)(ks * 96 + wn * 6)) * 512 + lane * 8;
#pragma unroll
    for (int kk = 0; kk < 4; kk++) {
      short8 ha0 = *(const short8*)&Hl[pb][wm + l15][kk * 32 + l4 * 8];
      short8 ha1 = *(const short8*)&Hl[pb][wm + 16 + l15][kk * 32 + l4 * 8];
#pragma unroll
      for (int j = 0; j < 6; j++) {
        short8 bf2 = *(const short8*)(w2b + kk * 12288 + j * 512);
        acc[0][j] = __builtin_amdgcn_mfma_f32_16x16x32_bf16(ha0, bf2, acc[0][j], 0, 0, 0);
        acc[1][j] = __builtin_amdgcn_mfma_f32_16x16x32_bf16(ha1, bf2, acc[1][j], 0, 0, 0);
      }
    }
  }
  // ---- epilogue: + b2 + residual ----
#pragma unroll
  for (int j = 0; j < 6; j++) {
    int n = wn * 96 + j * 16 + l15;
    float bv = B2[n];
#pragma unroll
    for (int i = 0; i < 2; i++)
#pragma unroll
      for (int r = 0; r < 4; r++) {
        int m = m0 + wm + i * 16 + l4 * 4 + r;
        OUT[(size_t)m * 384 + n] = acc[i][j][r] + bv + X2[(size_t)m * 384 + n];
      }
  }
}

// ---------------- MFMA window attention: 1 wave per (window, head) ----------------
__global__ __launch_bounds__(64) void attn_mfma(
    const __hip_bfloat16* __restrict__ qkv, const __hip_bfloat16* __restrict__ qkv_pad,
    const float* __restrict__ Bexp, __hip_bfloat16* __restrict__ aw) {
  int h = blockIdx.x % NHEAD;
  int w = blockIdx.x / NHEAD;
  int b = w / 25, wi = w % 25;
  int wh = wi / 5, wv = wi % 5;

  __shared__ unsigned short Q[64][40];
  __shared__ unsigned short K[64][40];
  __shared__ unsigned short Vt[32][72];
  __shared__ unsigned short P[64][72];

  int lane = threadIdx.x;
  int l15 = lane & 15, l4 = lane >> 4;

  {
    int t = lane;
    uint4 z = {0, 0, 0, 0};
    uint4 qv[4], kv[4];
    union { uint4 u[4]; unsigned short s[32]; } vu;
    bool use = t < 49;
    const unsigned short* src = (const unsigned short*)qkv_pad + h * 96;
    if (use) {
      int hh = wh * 7 + t / 7, ww = wv * 7 + t % 7;
      if (hh < 32 && ww < 32)
        src = (const unsigned short*)qkv + (size_t)(b * 1024 + hh * 32 + ww) * QKVC + h * 96;
    }
#pragma unroll
    for (int c = 0; c < 4; c++) {
      qv[c]   = use ? *(const uint4*)(src + c * 8)      : z;
      kv[c]   = use ? *(const uint4*)(src + 32 + c * 8) : z;
      vu.u[c] = use ? *(const uint4*)(src + 64 + c * 8) : z;
    }
#pragma unroll
    for (int c = 0; c < 4; c++) {
      *(uint4*)&Q[t][c * 8] = qv[c];
      *(uint4*)&K[t][c * 8] = kv[c];
    }
#pragma unroll
    for (int d = 0; d < 32; d++) Vt[d][t] = vu.s[d];
  }
  __syncthreads();

  f32x4 acc[4][4] = {};
  {
    short8 aq[4], bk[4];
#pragma unroll
    for (int i = 0; i < 4; i++) aq[i] = *(const short8*)&Q[i * 16 + l15][l4 * 8];
#pragma unroll
    for (int j = 0; j < 4; j++) bk[j] = *(const short8*)&K[j * 16 + l15][l4 * 8];
#pragma unroll
    for (int i = 0; i < 4; i++)
#pragma unroll
      for (int j = 0; j < 4; j++)
        acc[i][j] = __builtin_amdgcn_mfma_f32_16x16x32_bf16(aq[i], bk[j], acc[i][j], 0, 0, 0);
  }

  const float* Bh = Bexp + h * 4096;
  float rinv_[4][4];
#pragma unroll
  for (int i = 0; i < 4; i++) {
    float s[4][4];
#pragma unroll
    for (int j = 0; j < 4; j++)
#pragma unroll
      for (int r = 0; r < 4; r++) {
        int n = i * 16 + l4 * 4 + r, m = j * 16 + l15;
        s[j][r] = acc[i][j][r] * SCALE + Bh[n * 64 + m];
      }
#pragma unroll
    for (int r = 0; r < 4; r++) {
      float mx = fmaxf(fmaxf(s[0][r], s[1][r]), fmaxf(s[2][r], s[3][r]));
#pragma unroll
      for (int o = 1; o < 16; o <<= 1) mx = fmaxf(mx, __shfl_xor(mx, o));
      float p[4], sm = 0.f;
#pragma unroll
      for (int j = 0; j < 4; j++) { p[j] = __expf(s[j][r] - mx); sm += p[j]; }
#pragma unroll
      for (int o = 1; o < 16; o <<= 1) sm += __shfl_xor(sm, o);
      rinv_[i][r] = 1.f / sm;
      int n = i * 16 + l4 * 4 + r;
#pragma unroll
      for (int j = 0; j < 4; j++) P[n][j * 16 + l15] = f2bf(p[j]);
    }
  }
  __syncthreads();

  f32x4 o[4][2] = {};
#pragma unroll
  for (int ks = 0; ks < 2; ks++) {
    short8 pa[4], vb[2];
#pragma unroll
    for (int i = 0; i < 4; i++) pa[i] = *(const short8*)&P[i * 16 + l15][ks * 32 + l4 * 8];
#pragma unroll
    for (int j = 0; j < 2; j++) vb[j] = *(const short8*)&Vt[j * 16 + l15][ks * 32 + l4 * 8];
#pragma unroll
    for (int i = 0; i < 4; i++)
#pragma unroll
      for (int j = 0; j < 2; j++)
        o[i][j] = __builtin_amdgcn_mfma_f32_16x16x32_bf16(pa[i], vb[j], o[i][j], 0, 0, 0);
  }

#pragma unroll
  for (int i = 0; i < 4; i++)
#pragma unroll
    for (int r = 0; r < 4; r++) {
      int n = i * 16 + l4 * 4 + r;
      if (n < 49) {
        int hh = wh * 7 + n / 7, ww = wv * 7 + n % 7;
        if (hh < 32 && ww < 32) {
          __hip_bfloat16* dst = aw + (size_t)(b * 1024 + hh * 32 + ww) * CDIM + h * 32;
          float ri = rinv_[i][r];
#pragma unroll
          for (int j = 0; j < 2; j++)
            dst[j * 16 + l15] = __float2bfloat16(o[i][j][r] * ri);
        }
      }
    }
}

// ------- fused depthwise 3x3 conv + BN + LN2: block = (b, x, y-half), thread = channel -------
__global__ __launch_bounds__(384) void conv_bn_ln_kernel(
    const float* __restrict__ X, const float* __restrict__ W9,
    const float* __restrict__ g, const float* __restrict__ bb,
    const float* __restrict__ mm, const float* __restrict__ vv,
    const float* __restrict__ lg, const float* __restrict__ lb,
    float* __restrict__ X2, __hip_bfloat16* __restrict__ XN) {
  int nwg = gridDim.x;
  int id = blockIdx.x;
  int nid = (id & 7) * (nwg >> 3) + (id >> 3);
  int yh = nid & 1;
  int x = (nid >> 1) & 31;
  int b = nid >> 6;
  int c = threadIdx.x;

  float w[9];
#pragma unroll
  for (int i = 0; i < 9; i++) w[i] = W9[c * 9 + i];
  float bnsc = rsqrtf(vv[c] + 1e-5f) * g[c];
  float bnsh = bb[c] - mm[c] * bnsc;
  float lgc = lg[c], lbc = lb[c];

  bool xm = x > 0, xp = x < 31;
  const float* colbase = X + ((size_t)(b * 1024 + x)) * CDIM + c;

  __shared__ float part[2][6][2];
  int wv = threadIdx.x >> 6, ln = threadIdx.x & 63;

  float w0[3], w1[3], w2[3];
  int y0 = yh * 16;
  if (y0 == 0) {
    w0[0] = w0[1] = w0[2] = 0.f;
  } else {
    const float* p = colbase + (size_t)(y0 - 1) * 32 * CDIM;
    w0[0] = xm ? p[-CDIM] : 0.f; w0[1] = p[0]; w0[2] = xp ? p[CDIM] : 0.f;
  }
  {
    const float* p = colbase + (size_t)y0 * 32 * CDIM;
    w1[0] = xm ? p[-CDIM] : 0.f; w1[1] = p[0]; w1[2] = xp ? p[CDIM] : 0.f;
  }

  for (int y = y0; y < y0 + 16; y++) {
    if (y + 1 < 32) {
      const float* p = colbase + (size_t)(y + 1) * 32 * CDIM;
      w2[0] = xm ? p[-CDIM] : 0.f; w2[1] = p[0]; w2[2] = xp ? p[CDIM] : 0.f;
    } else {
      w2[0] = w2[1] = w2[2] = 0.f;
    }
    float acc = w0[0] * w[0] + w0[1] * w[1] + w0[2] * w[2]
              + w1[0] * w[3] + w1[1] * w[4] + w1[2] * w[5]
              + w2[0] * w[6] + w2[1] * w[7] + w2[2] * w[8];
    float r = acc * bnsc + bnsh;
    size_t tok = (size_t)(b * 1024 + y * 32 + x);
    X2[tok * CDIM + c] = r;

    float s1 = r, s2 = r * r;
#pragma unroll
    for (int o = 32; o > 0; o >>= 1) { s1 += __shfl_xor(s1, o); s2 += __shfl_xor(s2, o); }
    int pb = y & 1;
    if (ln == 0) { part[pb][wv][0] = s1; part[pb][wv][1] = s2; }
    __syncthreads();
    float ts1 = 0.f, ts2 = 0.f;
#pragma unroll
    for (int i = 0; i < 6; i++) { ts1 += part[pb][i][0]; ts2 += part[pb][i][1]; }
    float mean = ts1 * (1.f / 384.f);
    float var = ts2 * (1.f / 384.f) - mean * mean;
    float rstd = rsqrtf(var + 1e-5f);
    XN[tok * CDIM + c] = __float2bfloat16((r - mean) * rstd * lgc + lbc);

    w0[0] = w1[0]; w0[1] = w1[1]; w0[2] = w1[2];
    w1[0] = w2[0]; w1[1] = w2[1]; w1[2] = w2[2];
  }
}

extern "C" void kernel_launch(void* const* d_in, const int* in_sizes, int n_in,
                              void* d_out, int out_size, void* d_ws, size_t ws_size,
                              hipStream_t stream) {
  const float* x      = (const float*)d_in[0];
  const float* ln1_g  = (const float*)d_in[1];
  const float* ln1_b  = (const float*)d_in[2];
  const float* qkv_w  = (const float*)d_in[3];
  const float* qkv_b  = (const float*)d_in[4];
  const float* proj_w = (const float*)d_in[5];
  const float* proj_b = (const float*)d_in[6];
  const float* att_b  = (const float*)d_in[7];
  const float* conv_w = (const float*)d_in[8];
  const float* bn_g   = (const float*)d_in[9];
  const float* bn_b   = (const float*)d_in[10];
  const float* bn_m   = (const float*)d_in[11];
  const float* bn_v   = (const float*)d_in[12];
  const float* ln2_g  = (const float*)d_in[13];
  const float* ln2_b  = (const float*)d_in[14];
  const float* fc1_w  = (const float*)d_in[15];
  const float* fc1_b  = (const float*)d_in[16];
  const float* fc2_w  = (const float*)d_in[17];
  const float* fc2_b  = (const float*)d_in[18];
  const int* bias_idxs = (const int*)d_in[19];
  int n_off = in_sizes[7] / NHEAD;
  float* out = (float*)d_out;

  char* ws = (char*)d_ws;
  size_t off = 0;
  __hip_bfloat16* qkv_pad = (__hip_bfloat16*)(ws + off); off += QKVC * 2;
  off = (off + 255) & ~(size_t)255;
  float* Bexp = (float*)(ws + off); off += (size_t)NHEAD * 4096 * 4;
  __hip_bfloat16* wqkvT = (__hip_bfloat16*)(ws + off); off += (size_t)QKVC * CDIM * 2;
  __hip_bfloat16* wprojT = (__hip_bfloat16*)(ws + off); off += (size_t)CDIM * CDIM * 2;
  unsigned short* w1f = (unsigned short*)(ws + off); off += (size_t)MLPH * CDIM * 2;
  unsigned short* w2f = (unsigned short*)(ws + off); off += (size_t)CDIM * MLPH * 2;
  size_t HDR = (off + 255) & ~(size_t)255;

  // per-token chunk scratch (x1 aliases qkv):
  // xn bf16(768) + qkv/x1 (2304) + awb bf16(768) + x2 f32(1536) = 5376 B
  const size_t PER_TOK = 5376;
  int Bc = 64;
  while (Bc > 1 && HDR + (size_t)Bc * 1024 * PER_TOK > ws_size) Bc >>= 1;
  size_t Tc = (size_t)Bc * 1024;

  off = HDR;
  __hip_bfloat16* xn = (__hip_bfloat16*)(ws + off); off += Tc * CDIM * 2;
  __hip_bfloat16* qkv = (__hip_bfloat16*)(ws + off); off += Tc * QKVC * 2;
  float* x1 = (float*)qkv;  // alias: qkv dead after attn_mfma
  __hip_bfloat16* awb = (__hip_bfloat16*)(ws + off); off += Tc * CDIM * 2;
  float* x2 = (float*)(ws + off); off += Tc * CDIM * 4;

  pad_qkv_kernel<<<dim3(5), dim3(256), 0, stream>>>(ln1_b, qkv_w, qkv_b, qkv_pad);
  expand_bias<<<dim3(NHEAD), dim3(256), 0, stream>>>(att_b, bias_idxs, Bexp, n_off);
  wt_convert<<<dim3(QKVC / 32, CDIM / 32), dim3(32, 8), 0, stream>>>(qkv_w, wqkvT, CDIM, QKVC);
  wt_convert<<<dim3(CDIM / 32, CDIM / 32), dim3(32, 8), 0, stream>>>(proj_w, wprojT, CDIM, CDIM);
  wfrag1<<<dim3(1152), dim3(64), 0, stream>>>(fc1_w, w1f);
  wfrag2<<<dim3(1152), dim3(64), 0, stream>>>(fc2_w, w2f);

  for (int b0 = 0; b0 < 64; b0 += Bc) {
    const float* xa = x + (size_t)b0 * 1024 * CDIM;
    float* outa = out + (size_t)b0 * 1024 * CDIM;
    int M = (int)Tc;

    ln_kernel<<<dim3(M / 4), dim3(256), 0, stream>>>(xa, ln1_g, ln1_b, xn, M);
    gemm_mfma<0, 0, 1><<<dim3(QKVC / 64, M / 128), dim3(256), 0, stream>>>(
        xn, wqkvT, qkv_b, nullptr, qkv, M, QKVC, CDIM);
    attn_mfma<<<dim3(Bc * 25 * NHEAD), dim3(64), 0, stream>>>(qkv, qkv_pad, Bexp, awb);
    gemm_mfma<0, 1, 0><<<dim3(CDIM / 64, M / 128), dim3(256), 0, stream>>>(
        awb, wprojT, proj_b, xa, x1, M, CDIM, CDIM);
    conv_bn_ln_kernel<<<dim3(Bc * 64), dim3(384), 0, stream>>>(
        x1, conv_w, bn_g, bn_b, bn_m, bn_v, ln2_g, ln2_b, x2, xn);
    mlp_fused<<<dim3(M / 64), dim3(512), 0, stream>>>(
        xn, w1f, fc1_b, w2f, fc2_b, x2, outa);
  }
}

// Round 12
// 1076.310 us; speedup vs baseline: 1.0563x; 1.0563x over previous
//
#include <hip/hip_runtime.h>
#include <hip/hip_bf16.h>
#include <math.h>

#define NHEAD 12
#define CDIM 384
#define QKVC 1152
#define MLPH 1536
#define SCALE 0.17677669529663687f  // 32^-0.5

typedef __attribute__((ext_vector_type(8))) short short8;
typedef __attribute__((ext_vector_type(4))) float f32x4;

static __device__ __forceinline__ unsigned short f2bf(float f) {
  union { __hip_bfloat16 b; unsigned short u; } c;
  c.b = __float2bfloat16(f);
  return c.u;
}

// fast GELU (tanh form), NaN-safe; |err| vs exact erf-GELU < ~2e-4
static __device__ __forceinline__ float gelu_f(float x) {
  float x3 = x * x * x;
  float y = 0.7978845608028654f * (x + 0.044715f * x3);
  float e = __expf(2.f * y);
  float th = 1.f - 2.f / (e + 1.f);
  return 0.5f * x * (1.f + th);
}

// ---------------- LN (wave per token, C=384) -> bf16 out ----------------
__global__ void ln_kernel(const float* __restrict__ X, const float* __restrict__ g,
                          const float* __restrict__ b, __hip_bfloat16* __restrict__ Y, int T) {
  int wid = (blockIdx.x * blockDim.x + threadIdx.x) >> 6;
  int lane = threadIdx.x & 63;
  if (wid >= T) return;
  const float* x = X + (size_t)wid * CDIM;
  float vals[6];
  float s = 0.f;
#pragma unroll
  for (int i = 0; i < 6; i++) { vals[i] = x[lane + i * 64]; s += vals[i]; }
#pragma unroll
  for (int o = 32; o > 0; o >>= 1) s += __shfl_xor(s, o);
  float m = s * (1.f / 384.f);
  float vs = 0.f;
#pragma unroll
  for (int i = 0; i < 6; i++) { float d = vals[i] - m; vs += d * d; }
#pragma unroll
  for (int o = 32; o > 0; o >>= 1) vs += __shfl_xor(vs, o);
  float rs = rsqrtf(vs * (1.f / 384.f) + 1e-5f);
  __hip_bfloat16* y = Y + (size_t)wid * CDIM;
#pragma unroll
  for (int i = 0; i < 6; i++) {
    int c = lane + i * 64;
    y[c] = __float2bfloat16((vals[i] - m) * rs * g[c] + b[c]);
  }
}

// ------------- qkv of a padded (zero) token: ln1_b @ qkv_w + qkv_b -> bf16 -------------
__global__ void pad_qkv_kernel(const float* __restrict__ lb, const float* __restrict__ Wq,
                               const float* __restrict__ bq, __hip_bfloat16* __restrict__ outp) {
  int j = blockIdx.x * blockDim.x + threadIdx.x;
  if (j >= QKVC) return;
  float s = bq[j];
  for (int c = 0; c < CDIM; c++) s += lb[c] * Wq[(size_t)c * QKVC + j];
  outp[j] = __float2bfloat16(s);
}

// ------------- expand relative-position bias to padded [12][64][64] f32 -------------
__global__ void expand_bias(const float* __restrict__ biases, const int* __restrict__ bidx,
                            float* __restrict__ Bexp, int n_off) {
  int h = blockIdx.x;
  for (int e = threadIdx.x; e < 4096; e += 256) {
    int n = e >> 6, m = e & 63;
    float v;
    if (m >= 49) v = -1e30f;
    else if (n >= 49) v = 0.f;
    else v = biases[h * n_off + bidx[n * 49 + m]];
    Bexp[h * 4096 + e] = v;
  }
}

// ---------------- weight transpose + f32->bf16 convert: W[K][N] -> Wt[N][K] ----------------
__global__ void wt_convert(const float* __restrict__ W, __hip_bfloat16* __restrict__ Wt,
                           int K, int N) {
  __shared__ float t[32][33];
  int n0 = blockIdx.x * 32, k0 = blockIdx.y * 32;
  int tx = threadIdx.x, ty = threadIdx.y;  // 32 x 8
#pragma unroll
  for (int i = 0; i < 4; i++) t[ty + i * 8][tx] = W[(size_t)(k0 + ty + i * 8) * N + n0 + tx];
  __syncthreads();
#pragma unroll
  for (int i = 0; i < 4; i++)
    Wt[(size_t)(n0 + ty + i * 8) * K + k0 + tx] = __float2bfloat16(t[tx][ty + i * 8]);
}

// -------- pack fc1_w [384][1536] into phase-1 MFMA fragment order (1m x 8n waves) --------
__global__ void wfrag1(const float* __restrict__ W, unsigned short* __restrict__ WF) {
  int f = blockIdx.x;
  int lane = threadIdx.x;
  int wn = f & 7, kk = (f >> 3) % 12, ks = f / 96;
  int n = ks * 128 + wn * 16 + (lane & 15);
  int k = kk * 32 + (lane >> 4) * 8;
  unsigned short* dst = WF + ((size_t)f * 64 + lane) * 8;
#pragma unroll
  for (int j = 0; j < 8; j++) dst[j] = f2bf(W[(size_t)(k + j) * MLPH + n]);
}

// -------- pack fc2_w [1536][384] into phase-2 MFMA fragment order (1m x 8n waves) --------
__global__ void wfrag2(const float* __restrict__ W, unsigned short* __restrict__ WF) {
  int f = blockIdx.x;
  int lane = threadIdx.x;
  int j = f % 3, wn = (f / 3) & 7, kk = (f / 24) & 3, ks = f / 96;
  int n = wn * 48 + j * 16 + (lane & 15);
  int k = ks * 128 + kk * 32 + (lane >> 4) * 8;
  unsigned short* dst = WF + ((size_t)f * 64 + lane) * 8;
#pragma unroll
  for (int jj = 0; jj < 8; jj++) dst[jj] = f2bf(W[(size_t)(k + jj) * CDIM + n]);
}

// ---------------- bf16 MFMA GEMM, 128x128 tile, plain 2-D grid (no swizzle) ----------------
// A: M x K bf16 row-major. Bt: N x K bf16 row-major. 4 waves (2x2), wave = 64x64.
template <int GELU, int HAS_RES, int OUT_BF16>
__global__ __launch_bounds__(256) void gemm128(
    const __hip_bfloat16* __restrict__ A, const __hip_bfloat16* __restrict__ Bt,
    const float* __restrict__ bias, const float* __restrict__ res,
    void* __restrict__ Cout, int M, int N, int K) {
  __shared__ unsigned short Al[128][72];
  __shared__ unsigned short Bl[128][72];
  int tid = threadIdx.x;
  int m0 = blockIdx.y * 128, n0 = blockIdx.x * 128;
  int wave = tid >> 6, lane = tid & 63;
  int wm = (wave >> 1) * 64, wn = (wave & 1) * 64;
  int l15 = lane & 15, l4 = lane >> 4;

  int row = tid >> 1, cg = (tid & 1) * 32;
  const __hip_bfloat16* Ag = A + (size_t)(m0 + row) * K + cg;
  const __hip_bfloat16* Bg = Bt + (size_t)(n0 + row) * K + cg;

  f32x4 acc[4][4] = {};

  for (int kt = 0; kt < K; kt += 64) {
    uint4 av[4], bv[4];
#pragma unroll
    for (int i = 0; i < 4; i++) {
      av[i] = *(const uint4*)(Ag + kt + i * 8);
      bv[i] = *(const uint4*)(Bg + kt + i * 8);
    }
    __syncthreads();
#pragma unroll
    for (int i = 0; i < 4; i++) {
      *(uint4*)&Al[row][cg + i * 8] = av[i];
      *(uint4*)&Bl[row][cg + i * 8] = bv[i];
    }
    __syncthreads();
#pragma unroll
    for (int kk = 0; kk < 64; kk += 32) {
      short8 af[4], bfr[4];
#pragma unroll
      for (int i = 0; i < 4; i++)
        af[i] = *(const short8*)&Al[wm + i * 16 + l15][kk + l4 * 8];
#pragma unroll
      for (int j = 0; j < 4; j++)
        bfr[j] = *(const short8*)&Bl[wn + j * 16 + l15][kk + l4 * 8];
#pragma unroll
      for (int i = 0; i < 4; i++)
#pragma unroll
        for (int j = 0; j < 4; j++)
          acc[i][j] = __builtin_amdgcn_mfma_f32_16x16x32_bf16(af[i], bfr[j], acc[i][j], 0, 0, 0);
    }
  }

#pragma unroll
  for (int i = 0; i < 4; i++) {
#pragma unroll
    for (int j = 0; j < 4; j++) {
      int n = n0 + wn + j * 16 + l15;
      float bv = bias[n];
#pragma unroll
      for (int r = 0; r < 4; r++) {
        int m = m0 + wm + i * 16 + l4 * 4 + r;
        float c = acc[i][j][r] + bv;
        if (GELU) c = gelu_f(c);
        if (HAS_RES) c += res[(size_t)m * N + n];
        if (OUT_BF16)
          ((__hip_bfloat16*)Cout)[(size_t)m * N + n] = __float2bfloat16(c);
        else
          ((float*)Cout)[(size_t)m * N + n] = c;
      }
    }
  }
}

// ---------------- fused MLP (R10-verified best): 8 waves 1m x 8n, BM=64 ----------------
__global__ __launch_bounds__(512, 4) void mlp_fused(
    const __hip_bfloat16* __restrict__ XN, const unsigned short* __restrict__ W1F,
    const float* __restrict__ B1, const unsigned short* __restrict__ W2F,
    const float* __restrict__ B2, const float* __restrict__ X2,
    float* __restrict__ OUT) {
  __shared__ unsigned short XNl[64][388];
  __shared__ unsigned short Hl[64][132];
  int tid = threadIdx.x;
  int m0 = blockIdx.x * 64;
  int wave = tid >> 6, lane = tid & 63;
  int wn = wave;  // 8 n-groups
  int l15 = lane & 15, l4 = lane >> 4;

  {
#pragma unroll
    for (int i = 0; i < 6; i++) {
      int u = tid + i * 512;
      int r = u / 48, col = (u % 48) * 8;
      *(uint4*)&XNl[r][col] =
          *(const uint4*)((const unsigned short*)XN + (size_t)(m0 + r) * 384 + col);
    }
  }

  f32x4 acc[4][3] = {};
  __syncthreads();

  for (int ks = 0; ks < 12; ks++) {
    f32x4 hacc[4] = {};
    const unsigned short* w1fb = W1F + ((size_t)(ks * 96 + wn)) * 512 + lane * 8;
#pragma unroll
    for (int kk = 0; kk < 12; kk++) {
      short8 bf0 = *(const short8*)(w1fb + kk * 4096);
#pragma unroll
      for (int i = 0; i < 4; i++) {
        short8 af = *(const short8*)&XNl[i * 16 + l15][kk * 32 + l4 * 8];
        hacc[i] = __builtin_amdgcn_mfma_f32_16x16x32_bf16(af, bf0, hacc[i], 0, 0, 0);
      }
    }
    float b1v = B1[ks * 128 + wn * 16 + l15];
    __syncthreads();
#pragma unroll
    for (int i = 0; i < 4; i++)
#pragma unroll
      for (int r = 0; r < 4; r++) {
        float c = hacc[i][r] + b1v;
        Hl[i * 16 + l4 * 4 + r][wn * 16 + l15] = f2bf(gelu_f(c));
      }
    __syncthreads();
    const unsigned short* w2fb = W2F + ((size_t)(ks * 96 + wn * 3)) * 512 + lane * 8;
#pragma unroll
    for (int kk = 0; kk < 4; kk++) {
      short8 af2[4];
#pragma unroll
      for (int i = 0; i < 4; i++)
        af2[i] = *(const short8*)&Hl[i * 16 + l15][kk * 32 + l4 * 8];
#pragma unroll
      for (int j = 0; j < 3; j++) {
        short8 bf2 = *(const short8*)(w2fb + kk * 12288 + j * 512);
#pragma unroll
        for (int i = 0; i < 4; i++)
          acc[i][j] = __builtin_amdgcn_mfma_f32_16x16x32_bf16(af2[i], bf2, acc[i][j], 0, 0, 0);
      }
    }
  }
#pragma unroll
  for (int j = 0; j < 3; j++) {
    int n = wn * 48 + j * 16 + l15;
    float bv = B2[n];
#pragma unroll
    for (int i = 0; i < 4; i++)
#pragma unroll
      for (int r = 0; r < 4; r++) {
        int m = m0 + i * 16 + l4 * 4 + r;
        OUT[(size_t)m * 384 + n] = acc[i][j][r] + bv + X2[(size_t)m * 384 + n];
      }
  }
}

// ---------------- MFMA window attention: 1 wave per (window, head) ----------------
__global__ __launch_bounds__(64) void attn_mfma(
    const __hip_bfloat16* __restrict__ qkv, const __hip_bfloat16* __restrict__ qkv_pad,
    const float* __restrict__ Bexp, __hip_bfloat16* __restrict__ aw) {
  int h = blockIdx.x % NHEAD;
  int w = blockIdx.x / NHEAD;
  int b = w / 25, wi = w % 25;
  int wh = wi / 5, wv = wi % 5;

  __shared__ unsigned short Q[64][40];
  __shared__ unsigned short K[64][40];
  __shared__ unsigned short Vt[32][72];
  __shared__ unsigned short P[64][72];

  int lane = threadIdx.x;
  int l15 = lane & 15, l4 = lane >> 4;

  {
    int t = lane;
    uint4 z = {0, 0, 0, 0};
    uint4 qv[4], kv[4];
    union { uint4 u[4]; unsigned short s[32]; } vu;
    bool use = t < 49;
    const unsigned short* src = (const unsigned short*)qkv_pad + h * 96;
    if (use) {
      int hh = wh * 7 + t / 7, ww = wv * 7 + t % 7;
      if (hh < 32 && ww < 32)
        src = (const unsigned short*)qkv + (size_t)(b * 1024 + hh * 32 + ww) * QKVC + h * 96;
    }
#pragma unroll
    for (int c = 0; c < 4; c++) {
      qv[c]   = use ? *(const uint4*)(src + c * 8)      : z;
      kv[c]   = use ? *(const uint4*)(src + 32 + c * 8) : z;
      vu.u[c] = use ? *(const uint4*)(src + 64 + c * 8) : z;
    }
#pragma unroll
    for (int c = 0; c < 4; c++) {
      *(uint4*)&Q[t][c * 8] = qv[c];
      *(uint4*)&K[t][c * 8] = kv[c];
    }
#pragma unroll
    for (int d = 0; d < 32; d++) Vt[d][t] = vu.s[d];
  }
  __syncthreads();

  f32x4 acc[4][4] = {};
  {
    short8 aq[4], bk[4];
#pragma unroll
    for (int i = 0; i < 4; i++) aq[i] = *(const short8*)&Q[i * 16 + l15][l4 * 8];
#pragma unroll
    for (int j = 0; j < 4; j++) bk[j] = *(const short8*)&K[j * 16 + l15][l4 * 8];
#pragma unroll
    for (int i = 0; i < 4; i++)
#pragma unroll
      for (int j = 0; j < 4; j++)
        acc[i][j] = __builtin_amdgcn_mfma_f32_16x16x32_bf16(aq[i], bk[j], acc[i][j], 0, 0, 0);
  }

  const float* Bh = Bexp + h * 4096;
  float rinv_[4][4];
#pragma unroll
  for (int i = 0; i < 4; i++) {
    float s[4][4];
#pragma unroll
    for (int j = 0; j < 4; j++)
#pragma unroll
      for (int r = 0; r < 4; r++) {
        int n = i * 16 + l4 * 4 + r, m = j * 16 + l15;
        s[j][r] = acc[i][j][r] * SCALE + Bh[n * 64 + m];
      }
#pragma unroll
    for (int r = 0; r < 4; r++) {
      float mx = fmaxf(fmaxf(s[0][r], s[1][r]), fmaxf(s[2][r], s[3][r]));
#pragma unroll
      for (int o = 1; o < 16; o <<= 1) mx = fmaxf(mx, __shfl_xor(mx, o));
      float p[4], sm = 0.f;
#pragma unroll
      for (int j = 0; j < 4; j++) { p[j] = __expf(s[j][r] - mx); sm += p[j]; }
#pragma unroll
      for (int o = 1; o < 16; o <<= 1) sm += __shfl_xor(sm, o);
      rinv_[i][r] = 1.f / sm;
      int n = i * 16 + l4 * 4 + r;
#pragma unroll
      for (int j = 0; j < 4; j++) P[n][j * 16 + l15] = f2bf(p[j]);
    }
  }
  __syncthreads();

  f32x4 o[4][2] = {};
#pragma unroll
  for (int ks = 0; ks < 2; ks++) {
    short8 pa[4], vb[2];
#pragma unroll
    for (int i = 0; i < 4; i++) pa[i] = *(const short8*)&P[i * 16 + l15][ks * 32 + l4 * 8];
#pragma unroll
    for (int j = 0; j < 2; j++) vb[j] = *(const short8*)&Vt[j * 16 + l15][ks * 32 + l4 * 8];
#pragma unroll
    for (int i = 0; i < 4; i++)
#pragma unroll
      for (int j = 0; j < 2; j++)
        o[i][j] = __builtin_amdgcn_mfma_f32_16x16x32_bf16(pa[i], vb[j], o[i][j], 0, 0, 0);
  }

#pragma unroll
  for (int i = 0; i < 4; i++)
#pragma unroll
    for (int r = 0; r < 4; r++) {
      int n = i * 16 + l4 * 4 + r;
      if (n < 49) {
        int hh = wh * 7 + n / 7, ww = wv * 7 + n % 7;
        if (hh < 32 && ww < 32) {
          __hip_bfloat16* dst = aw + (size_t)(b * 1024 + hh * 32 + ww) * CDIM + h * 32;
          float ri = rinv_[i][r];
#pragma unroll
          for (int j = 0; j < 2; j++)
            dst[j * 16 + l15] = __float2bfloat16(o[i][j][r] * ri);
        }
      }
    }
}

// ---- fused depthwise 3x3 conv + BN + LN2: block = (b, x-quad, y-half), thread = channel ----
// 4 output columns per block: 6 column-loads per y-step for 4 pixels (1.5 loads/pixel vs 3).
__global__ __launch_bounds__(384) void conv_bn_ln_kernel(
    const float* __restrict__ X, const float* __restrict__ W9,
    const float* __restrict__ g, const float* __restrict__ bb,
    const float* __restrict__ mm, const float* __restrict__ vv,
    const float* __restrict__ lg, const float* __restrict__ lb,
    float* __restrict__ X2, __hip_bfloat16* __restrict__ XN) {
  int nwg = gridDim.x;          // Bc*16, multiple of 8
  int id = blockIdx.x;
  int nid = (id & 7) * (nwg >> 3) + (id >> 3);
  int yh = nid & 1;
  int xq = (nid >> 1) & 7;
  int b = nid >> 4;
  int c = threadIdx.x;

  float w[9];
#pragma unroll
  for (int i = 0; i < 9; i++) w[i] = W9[c * 9 + i];
  float bnsc = rsqrtf(vv[c] + 1e-5f) * g[c];
  float bnsh = bb[c] - mm[c] * bnsc;
  float lgc = lg[c], lbc = lb[c];

  int x0 = xq * 4;
  const float* base = X + (size_t)(b * 1024) * CDIM + c;

  __shared__ float part[2][6][4][2];
  int wv = c >> 6, ln = c & 63;

  float r0[6], r1[6], r2[6];

  int y0 = yh * 16;
  // load row y0-1 -> r0, row y0 -> r1 (columns x0-1 .. x0+4, zero-padded)
  {
    if (y0 == 0) {
#pragma unroll
      for (int k = 0; k < 6; k++) r0[k] = 0.f;
    } else {
      const float* p = base + (size_t)((y0 - 1) * 32) * CDIM;
#pragma unroll
      for (int k = 0; k < 6; k++) {
        int xx = x0 - 1 + k;
        r0[k] = (xx >= 0 && xx < 32) ? p[(size_t)xx * CDIM] : 0.f;
      }
    }
    const float* p = base + (size_t)(y0 * 32) * CDIM;
#pragma unroll
    for (int k = 0; k < 6; k++) {
      int xx = x0 - 1 + k;
      r1[k] = (xx >= 0 && xx < 32) ? p[(size_t)xx * CDIM] : 0.f;
    }
  }

  for (int y = y0; y < y0 + 16; y++) {
    if (y + 1 < 32) {
      const float* p = base + (size_t)((y + 1) * 32) * CDIM;
#pragma unroll
      for (int k = 0; k < 6; k++) {
        int xx = x0 - 1 + k;
        r2[k] = (xx >= 0 && xx < 32) ? p[(size_t)xx * CDIM] : 0.f;
      }
    } else {
#pragma unroll
      for (int k = 0; k < 6; k++) r2[k] = 0.f;
    }

    float rv[4], s1[4], s2[4];
#pragma unroll
    for (int px = 0; px < 4; px++) {
      float acc = r0[px] * w[0] + r0[px + 1] * w[1] + r0[px + 2] * w[2]
                + r1[px] * w[3] + r1[px + 1] * w[4] + r1[px + 2] * w[5]
                + r2[px] * w[6] + r2[px + 1] * w[7] + r2[px + 2] * w[8];
      rv[px] = acc * bnsc + bnsh;
      size_t tok = (size_t)(b * 1024 + y * 32 + x0 + px);
      X2[tok * CDIM + c] = rv[px];
      s1[px] = rv[px];
      s2[px] = rv[px] * rv[px];
    }
#pragma unroll
    for (int o = 32; o > 0; o >>= 1)
#pragma unroll
      for (int px = 0; px < 4; px++) {
        s1[px] += __shfl_xor(s1[px], o);
        s2[px] += __shfl_xor(s2[px], o);
      }
    int pb = y & 1;
    if (ln == 0)
#pragma unroll
      for (int px = 0; px < 4; px++) {
        part[pb][wv][px][0] = s1[px];
        part[pb][wv][px][1] = s2[px];
      }
    __syncthreads();
#pragma unroll
    for (int px = 0; px < 4; px++) {
      float ts1 = 0.f, ts2 = 0.f;
#pragma unroll
      for (int i = 0; i < 6; i++) { ts1 += part[pb][i][px][0]; ts2 += part[pb][i][px][1]; }
      float mean = ts1 * (1.f / 384.f);
      float var = ts2 * (1.f / 384.f) - mean * mean;
      float rstd = rsqrtf(var + 1e-5f);
      size_t tok = (size_t)(b * 1024 + y * 32 + x0 + px);
      XN[tok * CDIM + c] = __float2bfloat16((rv[px] - mean) * rstd * lgc + lbc);
    }
#pragma unroll
    for (int k = 0; k < 6; k++) { r0[k] = r1[k]; r1[k] = r2[k]; }
  }
}

extern "C" void kernel_launch(void* const* d_in, const int* in_sizes, int n_in,
                              void* d_out, int out_size, void* d_ws, size_t ws_size,
                              hipStream_t stream) {
  const float* x      = (const float*)d_in[0];
  const float* ln1_g  = (const float*)d_in[1];
  const float* ln1_b  = (const float*)d_in[2];
  const float* qkv_w  = (const float*)d_in[3];
  const float* qkv_b  = (const float*)d_in[4];
  const float* proj_w = (const float*)d_in[5];
  const float* proj_b = (const float*)d_in[6];
  const float* att_b  = (const float*)d_in[7];
  const float* conv_w = (const float*)d_in[8];
  const float* bn_g   = (const float*)d_in[9];
  const float* bn_b   = (const float*)d_in[10];
  const float* bn_m   = (const float*)d_in[11];
  const float* bn_v   = (const float*)d_in[12];
  const float* ln2_g  = (const float*)d_in[13];
  const float* ln2_b  = (const float*)d_in[14];
  const float* fc1_w  = (const float*)d_in[15];
  const float* fc1_b  = (const float*)d_in[16];
  const float* fc2_w  = (const float*)d_in[17];
  const float* fc2_b  = (const float*)d_in[18];
  const int* bias_idxs = (const int*)d_in[19];
  int n_off = in_sizes[7] / NHEAD;
  float* out = (float*)d_out;

  char* ws = (char*)d_ws;
  size_t off = 0;
  __hip_bfloat16* qkv_pad = (__hip_bfloat16*)(ws + off); off += QKVC * 2;
  off = (off + 255) & ~(size_t)255;
  float* Bexp = (float*)(ws + off); off += (size_t)NHEAD * 4096 * 4;
  __hip_bfloat16* wqkvT = (__hip_bfloat16*)(ws + off); off += (size_t)QKVC * CDIM * 2;
  __hip_bfloat16* wprojT = (__hip_bfloat16*)(ws + off); off += (size_t)CDIM * CDIM * 2;
  unsigned short* w1f = (unsigned short*)(ws + off); off += (size_t)MLPH * CDIM * 2;
  unsigned short* w2f = (unsigned short*)(ws + off); off += (size_t)CDIM * MLPH * 2;
  size_t HDR = (off + 255) & ~(size_t)255;

  // per-token chunk scratch (x1 aliases qkv):
  // xn bf16(768) + qkv/x1 (2304) + awb bf16(768) + x2 f32(1536) = 5376 B
  const size_t PER_TOK = 5376;
  int Bc = 64;
  while (Bc > 1 && HDR + (size_t)Bc * 1024 * PER_TOK > ws_size) Bc >>= 1;
  size_t Tc = (size_t)Bc * 1024;

  off = HDR;
  __hip_bfloat16* xn = (__hip_bfloat16*)(ws + off); off += Tc * CDIM * 2;
  __hip_bfloat16* qkv = (__hip_bfloat16*)(ws + off); off += Tc * QKVC * 2;
  float* x1 = (float*)qkv;  // alias: qkv dead after attn_mfma
  __hip_bfloat16* awb = (__hip_bfloat16*)(ws + off); off += Tc * CDIM * 2;
  float* x2 = (float*)(ws + off); off += Tc * CDIM * 4;

  pad_qkv_kernel<<<dim3(5), dim3(256), 0, stream>>>(ln1_b, qkv_w, qkv_b, qkv_pad);
  expand_bias<<<dim3(NHEAD), dim3(256), 0, stream>>>(att_b, bias_idxs, Bexp, n_off);
  wt_convert<<<dim3(QKVC / 32, CDIM / 32), dim3(32, 8), 0, stream>>>(qkv_w, wqkvT, CDIM, QKVC);
  wt_convert<<<dim3(CDIM / 32, CDIM / 32), dim3(32, 8), 0, stream>>>(proj_w, wprojT, CDIM, CDIM);
  wfrag1<<<dim3(1152), dim3(64), 0, stream>>>(fc1_w, w1f);
  wfrag2<<<dim3(1152), dim3(64), 0, stream>>>(fc2_w, w2f);

  for (int b0 = 0; b0 < 64; b0 += Bc) {
    const float* xa = x + (size_t)b0 * 1024 * CDIM;
    float* outa = out + (size_t)b0 * 1024 * CDIM;
    int M = (int)Tc;

    ln_kernel<<<dim3(M / 4), dim3(256), 0, stream>>>(xa, ln1_g, ln1_b, xn, M);
    gemm128<0, 0, 1><<<dim3(QKVC / 128, M / 128), dim3(256), 0, stream>>>(
        xn, wqkvT, qkv_b, nullptr, qkv, M, QKVC, CDIM);
    attn_mfma<<<dim3(Bc * 25 * NHEAD), dim3(64), 0, stream>>>(qkv, qkv_pad, Bexp, awb);
    gemm128<0, 1, 0><<<dim3(CDIM / 128, M / 128), dim3(256), 0, stream>>>(
        awb, wprojT, proj_b, xa, x1, M, CDIM, CDIM);
    conv_bn_ln_kernel<<<dim3(Bc * 16), dim3(384), 0, stream>>>(
        x1, conv_w, bn_g, bn_b, bn_m, bn_v, ln2_g, ln2_b, x2, xn);
    mlp_fused<<<dim3(M / 64), dim3(512), 0, stream>>>(
        xn, w1f, fc1_b, w2f, fc2_b, x2, outa);
  }
}

// Round 13
// 905.130 us; speedup vs baseline: 1.2560x; 1.1891x over previous
//
#include <hip/hip_runtime.h>
#include <hip/hip_bf16.h>
#include <math.h>

#define NHEAD 12
#define CDIM 384
#define QKVC 1152
#define MLPH 1536
#define SCALE 0.17677669529663687f  // 32^-0.5

typedef __attribute__((ext_vector_type(8))) short short8;
typedef __attribute__((ext_vector_type(4))) float f32x4;

static __device__ __forceinline__ unsigned short f2bf(float f) {
  union { __hip_bfloat16 b; unsigned short u; } c;
  c.b = __float2bfloat16(f);
  return c.u;
}

// fast GELU (tanh form), NaN-safe; |err| vs exact erf-GELU < ~2e-4
static __device__ __forceinline__ float gelu_f(float x) {
  float x3 = x * x * x;
  float y = 0.7978845608028654f * (x + 0.044715f * x3);
  float e = __expf(2.f * y);
  float th = 1.f - 2.f / (e + 1.f);
  return 0.5f * x * (1.f + th);
}

// ---------------- LN (wave per token, C=384) -> bf16 out ----------------
__global__ void ln_kernel(const float* __restrict__ X, const float* __restrict__ g,
                          const float* __restrict__ b, __hip_bfloat16* __restrict__ Y, int T) {
  int wid = (blockIdx.x * blockDim.x + threadIdx.x) >> 6;
  int lane = threadIdx.x & 63;
  if (wid >= T) return;
  const float* x = X + (size_t)wid * CDIM;
  float vals[6];
  float s = 0.f;
#pragma unroll
  for (int i = 0; i < 6; i++) { vals[i] = x[lane + i * 64]; s += vals[i]; }
#pragma unroll
  for (int o = 32; o > 0; o >>= 1) s += __shfl_xor(s, o);
  float m = s * (1.f / 384.f);
  float vs = 0.f;
#pragma unroll
  for (int i = 0; i < 6; i++) { float d = vals[i] - m; vs += d * d; }
#pragma unroll
  for (int o = 32; o > 0; o >>= 1) vs += __shfl_xor(vs, o);
  float rs = rsqrtf(vs * (1.f / 384.f) + 1e-5f);
  __hip_bfloat16* y = Y + (size_t)wid * CDIM;
#pragma unroll
  for (int i = 0; i < 6; i++) {
    int c = lane + i * 64;
    y[c] = __float2bfloat16((vals[i] - m) * rs * g[c] + b[c]);
  }
}

// ------------- qkv of a padded (zero) token: ln1_b @ qkv_w + qkv_b -> bf16 -------------
__global__ void pad_qkv_kernel(const float* __restrict__ lb, const float* __restrict__ Wq,
                               const float* __restrict__ bq, __hip_bfloat16* __restrict__ outp) {
  int j = blockIdx.x * blockDim.x + threadIdx.x;
  if (j >= QKVC) return;
  float s = bq[j];
  for (int c = 0; c < CDIM; c++) s += lb[c] * Wq[(size_t)c * QKVC + j];
  outp[j] = __float2bfloat16(s);
}

// ------------- expand relative-position bias to padded [12][64][64] f32 -------------
__global__ void expand_bias(const float* __restrict__ biases, const int* __restrict__ bidx,
                            float* __restrict__ Bexp, int n_off) {
  int h = blockIdx.x;
  for (int e = threadIdx.x; e < 4096; e += 256) {
    int n = e >> 6, m = e & 63;
    float v;
    if (m >= 49) v = -1e30f;
    else if (n >= 49) v = 0.f;
    else v = biases[h * n_off + bidx[n * 49 + m]];
    Bexp[h * 4096 + e] = v;
  }
}

// ---------------- weight transpose + f32->bf16 convert: W[K][N] -> Wt[N][K] ----------------
__global__ void wt_convert(const float* __restrict__ W, __hip_bfloat16* __restrict__ Wt,
                           int K, int N) {
  __shared__ float t[32][33];
  int n0 = blockIdx.x * 32, k0 = blockIdx.y * 32;
  int tx = threadIdx.x, ty = threadIdx.y;  // 32 x 8
#pragma unroll
  for (int i = 0; i < 4; i++) t[ty + i * 8][tx] = W[(size_t)(k0 + ty + i * 8) * N + n0 + tx];
  __syncthreads();
#pragma unroll
  for (int i = 0; i < 4; i++)
    Wt[(size_t)(n0 + ty + i * 8) * K + k0 + tx] = __float2bfloat16(t[tx][ty + i * 8]);
}

// -------- pack fc1_w [384][1536] into MFMA fragment order: f = ks*96 + kk*8 + g --------
// lane holds B[n][k]: n = ks*128 + g*16 + (lane&15), k = kk*32 + (lane>>4)*8 + j
__global__ void wfrag1(const float* __restrict__ W, unsigned short* __restrict__ WF) {
  int f = blockIdx.x;
  int lane = threadIdx.x;
  int g = f & 7, kk = (f >> 3) % 12, ks = f / 96;
  int n = ks * 128 + g * 16 + (lane & 15);
  int k = kk * 32 + (lane >> 4) * 8;
  unsigned short* dst = WF + ((size_t)f * 64 + lane) * 8;
#pragma unroll
  for (int j = 0; j < 8; j++) dst[j] = f2bf(W[(size_t)(k + j) * MLPH + n]);
}

// -------- pack fc2_w [1536][384] into MFMA fragment order: f = ks*96 + kk*24 + g2 --------
// lane holds B[n][k]: n = g2*16 + (lane&15), k = ks*128 + kk*32 + (lane>>4)*8 + jj
__global__ void wfrag2(const float* __restrict__ W, unsigned short* __restrict__ WF) {
  int f = blockIdx.x;
  int lane = threadIdx.x;
  int g2 = f % 24, kk = (f / 24) & 3, ks = f / 96;
  int n = g2 * 16 + (lane & 15);
  int k = ks * 128 + kk * 32 + (lane >> 4) * 8;
  unsigned short* dst = WF + ((size_t)f * 64 + lane) * 8;
#pragma unroll
  for (int jj = 0; jj < 8; jj++) dst[jj] = f2bf(W[(size_t)(k + jj) * CDIM + n]);
}

// ---------------- bf16 MFMA GEMM (128x64, R4 form): C = A @ Bt^T + bias (+res) ----------------
template <int GELU, int HAS_RES, int OUT_BF16>
__global__ __launch_bounds__(256) void gemm_mfma(
    const __hip_bfloat16* __restrict__ A, const __hip_bfloat16* __restrict__ Bt,
    const float* __restrict__ bias, const float* __restrict__ res,
    void* __restrict__ Cout, int M, int N, int K) {
  __shared__ unsigned short Al[128][72];
  __shared__ unsigned short Bl[64][72];
  int tid = threadIdx.x;
  int m0 = blockIdx.y * 128, n0 = blockIdx.x * 64;
  int wave = tid >> 6, lane = tid & 63;
  int wm = (wave >> 1) * 64, wn = (wave & 1) * 32;
  int l15 = lane & 15, l4 = lane >> 4;

  int am = tid >> 1, ak = (tid & 1) * 32;
  int bn = tid >> 2, bk = (tid & 3) * 16;
  const __hip_bfloat16* Ag = A + (size_t)(m0 + am) * K + ak;
  const __hip_bfloat16* Bg = Bt + (size_t)(n0 + bn) * K + bk;

  f32x4 acc[4][2] = {};

  for (int kt = 0; kt < K; kt += 64) {
    uint4 av0 = *(const uint4*)(Ag + kt);
    uint4 av1 = *(const uint4*)(Ag + kt + 8);
    uint4 av2 = *(const uint4*)(Ag + kt + 16);
    uint4 av3 = *(const uint4*)(Ag + kt + 24);
    uint4 bv0 = *(const uint4*)(Bg + kt);
    uint4 bv1 = *(const uint4*)(Bg + kt + 8);
    __syncthreads();
    *(uint4*)&Al[am][ak]      = av0;
    *(uint4*)&Al[am][ak + 8]  = av1;
    *(uint4*)&Al[am][ak + 16] = av2;
    *(uint4*)&Al[am][ak + 24] = av3;
    *(uint4*)&Bl[bn][bk]      = bv0;
    *(uint4*)&Bl[bn][bk + 8]  = bv1;
    __syncthreads();
#pragma unroll
    for (int kk = 0; kk < 64; kk += 32) {
      short8 af[4], bfr[2];
#pragma unroll
      for (int i = 0; i < 4; i++)
        af[i] = *(const short8*)&Al[wm + i * 16 + l15][kk + l4 * 8];
#pragma unroll
      for (int j = 0; j < 2; j++)
        bfr[j] = *(const short8*)&Bl[wn + j * 16 + l15][kk + l4 * 8];
#pragma unroll
      for (int i = 0; i < 4; i++)
#pragma unroll
        for (int j = 0; j < 2; j++)
          acc[i][j] = __builtin_amdgcn_mfma_f32_16x16x32_bf16(af[i], bfr[j], acc[i][j], 0, 0, 0);
    }
  }

#pragma unroll
  for (int i = 0; i < 4; i++) {
#pragma unroll
    for (int j = 0; j < 2; j++) {
      int n = n0 + wn + j * 16 + l15;
      float bv = bias[n];
#pragma unroll
      for (int r = 0; r < 4; r++) {
        int m = m0 + wm + i * 16 + l4 * 4 + r;
        float c = acc[i][j][r] + bv;
        if (GELU) c = gelu_f(c);
        if (HAS_RES) c += res[(size_t)m * N + n];
        if (OUT_BF16)
          ((__hip_bfloat16*)Cout)[(size_t)m * N + n] = __float2bfloat16(c);
        else
          ((float*)Cout)[(size_t)m * N + n] = c;
      }
    }
  }
}

// ---------- fused MLP, producer-consumer wave specialization ----------
// 8 waves: waves 0-3 = fc1 producers (weights->MFMA->GELU->Hl[t&1]),
// waves 4-7 = fc2 consumers (Hl[(t-1)&1]->MFMA->acc). 13-step pipeline,
// ONE barrier per step; H double-buffered; producer & consumer run
// CONCURRENTLY on each SIMD (1 producer + 1 consumer wave).
__global__ __launch_bounds__(512, 2) void mlp_pc(
    const __hip_bfloat16* __restrict__ XN, const unsigned short* __restrict__ W1F,
    const float* __restrict__ B1, const unsigned short* __restrict__ W2F,
    const float* __restrict__ B2, const float* __restrict__ X2,
    float* __restrict__ OUT) {
  __shared__ unsigned short XNl[64][388];     // 49664 B
  __shared__ unsigned short Hl[2][64][132];   // 33792 B  (total 83456 -> 1 block/CU)
  int tid = threadIdx.x;
  int m0 = blockIdx.x * 64;
  int wave = tid >> 6, lane = tid & 63;
  int role = wave >> 2;   // 0 = producer (fc1), 1 = consumer (fc2)
  int w4 = wave & 3;
  int l15 = lane & 15, l4 = lane >> 4;

  {  // stage A panel 64x384 bf16, fully coalesced (all 512 threads)
#pragma unroll
    for (int i = 0; i < 6; i++) {
      int u = tid + i * 512;
      int r = u / 48, col = (u % 48) * 8;
      *(uint4*)&XNl[r][col] =
          *(const uint4*)((const unsigned short*)XN + (size_t)(m0 + r) * 384 + col);
    }
  }
  __syncthreads();

  f32x4 acc[4][6] = {};  // consumer: 64 rows x 96 cols (4 m-tiles x 6 n-16groups)

  for (int t = 0; t < 13; t++) {
    if (role == 0) {
      if (t < 12) {
        int ks = t;
        // producer owns h-groups g = w4*2 .. w4*2+1 of the 128-wide slab
        f32x4 hacc[4][2] = {};
        const unsigned short* w1b = W1F + ((size_t)(ks * 96 + w4 * 2)) * 512 + lane * 8;
#pragma unroll
        for (int kk = 0; kk < 12; kk++) {
          short8 bf0 = *(const short8*)(w1b + kk * 4096);
          short8 bf1 = *(const short8*)(w1b + kk * 4096 + 512);
#pragma unroll
          for (int i = 0; i < 4; i++) {
            short8 af = *(const short8*)&XNl[i * 16 + l15][kk * 32 + l4 * 8];
            hacc[i][0] = __builtin_amdgcn_mfma_f32_16x16x32_bf16(af, bf0, hacc[i][0], 0, 0, 0);
            hacc[i][1] = __builtin_amdgcn_mfma_f32_16x16x32_bf16(af, bf1, hacc[i][1], 0, 0, 0);
          }
        }
        float b10 = B1[ks * 128 + w4 * 32 + l15];
        float b11 = B1[ks * 128 + w4 * 32 + 16 + l15];
        int pb = t & 1;
#pragma unroll
        for (int i = 0; i < 4; i++)
#pragma unroll
          for (int gi = 0; gi < 2; gi++) {
            float bv = gi ? b11 : b10;
#pragma unroll
            for (int r = 0; r < 4; r++) {
              float c = hacc[i][gi][r] + bv;
              Hl[pb][i * 16 + l4 * 4 + r][w4 * 32 + gi * 16 + l15] = f2bf(gelu_f(c));
            }
          }
      }
    } else {
      if (t > 0) {
        int ks = t - 1;
        int pb = ks & 1;
        // consumer owns out-col groups g2 = w4*6 .. w4*6+5  (n = 16*g2)
        const unsigned short* w2b = W2F + ((size_t)(ks * 96 + w4 * 6)) * 512 + lane * 8;
#pragma unroll
        for (int kk = 0; kk < 4; kk++) {
          short8 ha[4];
#pragma unroll
          for (int i = 0; i < 4; i++)
            ha[i] = *(const short8*)&Hl[pb][i * 16 + l15][kk * 32 + l4 * 8];
#pragma unroll
          for (int j = 0; j < 6; j++) {
            short8 bf2 = *(const short8*)(w2b + kk * 12288 + j * 512);
#pragma unroll
            for (int i = 0; i < 4; i++)
              acc[i][j] = __builtin_amdgcn_mfma_f32_16x16x32_bf16(ha[i], bf2, acc[i][j], 0, 0, 0);
          }
        }
      }
    }
    __syncthreads();
  }

  // ---- epilogue (consumers): + b2 + residual ----
  if (role == 1) {
#pragma unroll
    for (int j = 0; j < 6; j++) {
      int n = (w4 * 6 + j) * 16 + l15;
      float bv = B2[n];
#pragma unroll
      for (int i = 0; i < 4; i++)
#pragma unroll
        for (int r = 0; r < 4; r++) {
          int m = m0 + i * 16 + l4 * 4 + r;
          OUT[(size_t)m * 384 + n] = acc[i][j][r] + bv + X2[(size_t)m * 384 + n];
        }
    }
  }
}

// ---------------- MFMA window attention: 1 wave per (window, head) ----------------
__global__ __launch_bounds__(64) void attn_mfma(
    const __hip_bfloat16* __restrict__ qkv, const __hip_bfloat16* __restrict__ qkv_pad,
    const float* __restrict__ Bexp, __hip_bfloat16* __restrict__ aw) {
  int h = blockIdx.x % NHEAD;
  int w = blockIdx.x / NHEAD;
  int b = w / 25, wi = w % 25;
  int wh = wi / 5, wv = wi % 5;

  __shared__ unsigned short Q[64][40];
  __shared__ unsigned short K[64][40];
  __shared__ unsigned short Vt[32][72];
  __shared__ unsigned short P[64][72];

  int lane = threadIdx.x;
  int l15 = lane & 15, l4 = lane >> 4;

  {
    int t = lane;
    uint4 z = {0, 0, 0, 0};
    uint4 qv[4], kv[4];
    union { uint4 u[4]; unsigned short s[32]; } vu;
    bool use = t < 49;
    const unsigned short* src = (const unsigned short*)qkv_pad + h * 96;
    if (use) {
      int hh = wh * 7 + t / 7, ww = wv * 7 + t % 7;
      if (hh < 32 && ww < 32)
        src = (const unsigned short*)qkv + (size_t)(b * 1024 + hh * 32 + ww) * QKVC + h * 96;
    }
#pragma unroll
    for (int c = 0; c < 4; c++) {
      qv[c]   = use ? *(const uint4*)(src + c * 8)      : z;
      kv[c]   = use ? *(const uint4*)(src + 32 + c * 8) : z;
      vu.u[c] = use ? *(const uint4*)(src + 64 + c * 8) : z;
    }
#pragma unroll
    for (int c = 0; c < 4; c++) {
      *(uint4*)&Q[t][c * 8] = qv[c];
      *(uint4*)&K[t][c * 8] = kv[c];
    }
#pragma unroll
    for (int d = 0; d < 32; d++) Vt[d][t] = vu.s[d];
  }
  __syncthreads();

  f32x4 acc[4][4] = {};
  {
    short8 aq[4], bk[4];
#pragma unroll
    for (int i = 0; i < 4; i++) aq[i] = *(const short8*)&Q[i * 16 + l15][l4 * 8];
#pragma unroll
    for (int j = 0; j < 4; j++) bk[j] = *(const short8*)&K[j * 16 + l15][l4 * 8];
#pragma unroll
    for (int i = 0; i < 4; i++)
#pragma unroll
      for (int j = 0; j < 4; j++)
        acc[i][j] = __builtin_amdgcn_mfma_f32_16x16x32_bf16(aq[i], bk[j], acc[i][j], 0, 0, 0);
  }

  const float* Bh = Bexp + h * 4096;
  float rinv_[4][4];
#pragma unroll
  for (int i = 0; i < 4; i++) {
    float s[4][4];
#pragma unroll
    for (int j = 0; j < 4; j++)
#pragma unroll
      for (int r = 0; r < 4; r++) {
        int n = i * 16 + l4 * 4 + r, m = j * 16 + l15;
        s[j][r] = acc[i][j][r] * SCALE + Bh[n * 64 + m];
      }
#pragma unroll
    for (int r = 0; r < 4; r++) {
      float mx = fmaxf(fmaxf(s[0][r], s[1][r]), fmaxf(s[2][r], s[3][r]));
#pragma unroll
      for (int o = 1; o < 16; o <<= 1) mx = fmaxf(mx, __shfl_xor(mx, o));
      float p[4], sm = 0.f;
#pragma unroll
      for (int j = 0; j < 4; j++) { p[j] = __expf(s[j][r] - mx); sm += p[j]; }
#pragma unroll
      for (int o = 1; o < 16; o <<= 1) sm += __shfl_xor(sm, o);
      rinv_[i][r] = 1.f / sm;
      int n = i * 16 + l4 * 4 + r;
#pragma unroll
      for (int j = 0; j < 4; j++) P[n][j * 16 + l15] = f2bf(p[j]);
    }
  }
  __syncthreads();

  f32x4 o[4][2] = {};
#pragma unroll
  for (int ks = 0; ks < 2; ks++) {
    short8 pa[4], vb[2];
#pragma unroll
    for (int i = 0; i < 4; i++) pa[i] = *(const short8*)&P[i * 16 + l15][ks * 32 + l4 * 8];
#pragma unroll
    for (int j = 0; j < 2; j++) vb[j] = *(const short8*)&Vt[j * 16 + l15][ks * 32 + l4 * 8];
#pragma unroll
    for (int i = 0; i < 4; i++)
#pragma unroll
      for (int j = 0; j < 2; j++)
        o[i][j] = __builtin_amdgcn_mfma_f32_16x16x32_bf16(pa[i], vb[j], o[i][j], 0, 0, 0);
  }

#pragma unroll
  for (int i = 0; i < 4; i++)
#pragma unroll
    for (int r = 0; r < 4; r++) {
      int n = i * 16 + l4 * 4 + r;
      if (n < 49) {
        int hh = wh * 7 + n / 7, ww = wv * 7 + n % 7;
        if (hh < 32 && ww < 32) {
          __hip_bfloat16* dst = aw + (size_t)(b * 1024 + hh * 32 + ww) * CDIM + h * 32;
          float ri = rinv_[i][r];
#pragma unroll
          for (int j = 0; j < 2; j++)
            dst[j * 16 + l15] = __float2bfloat16(o[i][j][r] * ri);
        }
      }
    }
}

// ------- fused depthwise 3x3 conv + BN + LN2: block = (b, x, y-half), thread = channel -------
__global__ __launch_bounds__(384) void conv_bn_ln_kernel(
    const float* __restrict__ X, const float* __restrict__ W9,
    const float* __restrict__ g, const float* __restrict__ bb,
    const float* __restrict__ mm, const float* __restrict__ vv,
    const float* __restrict__ lg, const float* __restrict__ lb,
    float* __restrict__ X2, __hip_bfloat16* __restrict__ XN) {
  int nwg = gridDim.x;
  int id = blockIdx.x;
  int nid = (id & 7) * (nwg >> 3) + (id >> 3);
  int yh = nid & 1;
  int x = (nid >> 1) & 31;
  int b = nid >> 6;
  int c = threadIdx.x;

  float w[9];
#pragma unroll
  for (int i = 0; i < 9; i++) w[i] = W9[c * 9 + i];
  float bnsc = rsqrtf(vv[c] + 1e-5f) * g[c];
  float bnsh = bb[c] - mm[c] * bnsc;
  float lgc = lg[c], lbc = lb[c];

  bool xm = x > 0, xp = x < 31;
  const float* colbase = X + ((size_t)(b * 1024 + x)) * CDIM + c;

  __shared__ float part[2][6][2];
  int wv = threadIdx.x >> 6, ln = threadIdx.x & 63;

  float w0[3], w1[3], w2[3];
  int y0 = yh * 16;
  if (y0 == 0) {
    w0[0] = w0[1] = w0[2] = 0.f;
  } else {
    const float* p = colbase + (size_t)(y0 - 1) * 32 * CDIM;
    w0[0] = xm ? p[-CDIM] : 0.f; w0[1] = p[0]; w0[2] = xp ? p[CDIM] : 0.f;
  }
  {
    const float* p = colbase + (size_t)y0 * 32 * CDIM;
    w1[0] = xm ? p[-CDIM] : 0.f; w1[1] = p[0]; w1[2] = xp ? p[CDIM] : 0.f;
  }

  for (int y = y0; y < y0 + 16; y++) {
    if (y + 1 < 32) {
      const float* p = colbase + (size_t)(y + 1) * 32 * CDIM;
      w2[0] = xm ? p[-CDIM] : 0.f; w2[1] = p[0]; w2[2] = xp ? p[CDIM] : 0.f;
    } else {
      w2[0] = w2[1] = w2[2] = 0.f;
    }
    float acc = w0[0] * w[0] + w0[1] * w[1] + w0[2] * w[2]
              + w1[0] * w[3] + w1[1] * w[4] + w1[2] * w[5]
              + w2[0] * w[6] + w2[1] * w[7] + w2[2] * w[8];
    float r = acc * bnsc + bnsh;
    size_t tok = (size_t)(b * 1024 + y * 32 + x);
    X2[tok * CDIM + c] = r;

    float s1 = r, s2 = r * r;
#pragma unroll
    for (int o = 32; o > 0; o >>= 1) { s1 += __shfl_xor(s1, o); s2 += __shfl_xor(s2, o); }
    int pb = y & 1;
    if (ln == 0) { part[pb][wv][0] = s1; part[pb][wv][1] = s2; }
    __syncthreads();
    float ts1 = 0.f, ts2 = 0.f;
#pragma unroll
    for (int i = 0; i < 6; i++) { ts1 += part[pb][i][0]; ts2 += part[pb][i][1]; }
    float mean = ts1 * (1.f / 384.f);
    float var = ts2 * (1.f / 384.f) - mean * mean;
    float rstd = rsqrtf(var + 1e-5f);
    XN[tok * CDIM + c] = __float2bfloat16((r - mean) * rstd * lgc + lbc);

    w0[0] = w1[0]; w0[1] = w1[1]; w0[2] = w1[2];
    w1[0] = w2[0]; w1[1] = w2[1]; w1[2] = w2[2];
  }
}

extern "C" void kernel_launch(void* const* d_in, const int* in_sizes, int n_in,
                              void* d_out, int out_size, void* d_ws, size_t ws_size,
                              hipStream_t stream) {
  const float* x      = (const float*)d_in[0];
  const float* ln1_g  = (const float*)d_in[1];
  const float* ln1_b  = (const float*)d_in[2];
  const float* qkv_w  = (const float*)d_in[3];
  const float* qkv_b  = (const float*)d_in[4];
  const float* proj_w = (const float*)d_in[5];
  const float* proj_b = (const float*)d_in[6];
  const float* att_b  = (const float*)d_in[7];
  const float* conv_w = (const float*)d_in[8];
  const float* bn_g   = (const float*)d_in[9];
  const float* bn_b   = (const float*)d_in[10];
  const float* bn_m   = (const float*)d_in[11];
  const float* bn_v   = (const float*)d_in[12];
  const float* ln2_g  = (const float*)d_in[13];
  const float* ln2_b  = (const float*)d_in[14];
  const float* fc1_w  = (const float*)d_in[15];
  const float* fc1_b  = (const float*)d_in[16];
  const float* fc2_w  = (const float*)d_in[17];
  const float* fc2_b  = (const float*)d_in[18];
  const int* bias_idxs = (const int*)d_in[19];
  int n_off = in_sizes[7] / NHEAD;
  float* out = (float*)d_out;

  char* ws = (char*)d_ws;
  size_t off = 0;
  __hip_bfloat16* qkv_pad = (__hip_bfloat16*)(ws + off); off += QKVC * 2;
  off = (off + 255) & ~(size_t)255;
  float* Bexp = (float*)(ws + off); off += (size_t)NHEAD * 4096 * 4;
  __hip_bfloat16* wqkvT = (__hip_bfloat16*)(ws + off); off += (size_t)QKVC * CDIM * 2;
  __hip_bfloat16* wprojT = (__hip_bfloat16*)(ws + off); off += (size_t)CDIM * CDIM * 2;
  unsigned short* w1f = (unsigned short*)(ws + off); off += (size_t)MLPH * CDIM * 2;
  unsigned short* w2f = (unsigned short*)(ws + off); off += (size_t)CDIM * MLPH * 2;
  size_t HDR = (off + 255) & ~(size_t)255;

  // per-token chunk scratch (x1 aliases qkv):
  // xn bf16(768) + qkv/x1 (2304) + awb bf16(768) + x2 f32(1536) = 5376 B
  const size_t PER_TOK = 5376;
  int Bc = 64;
  while (Bc > 1 && HDR + (size_t)Bc * 1024 * PER_TOK > ws_size) Bc >>= 1;
  size_t Tc = (size_t)Bc * 1024;

  off = HDR;
  __hip_bfloat16* xn = (__hip_bfloat16*)(ws + off); off += Tc * CDIM * 2;
  __hip_bfloat16* qkv = (__hip_bfloat16*)(ws + off); off += Tc * QKVC * 2;
  float* x1 = (float*)qkv;  // alias: qkv dead after attn_mfma
  __hip_bfloat16* awb = (__hip_bfloat16*)(ws + off); off += Tc * CDIM * 2;
  float* x2 = (float*)(ws + off); off += Tc * CDIM * 4;

  pad_qkv_kernel<<<dim3(5), dim3(256), 0, stream>>>(ln1_b, qkv_w, qkv_b, qkv_pad);
  expand_bias<<<dim3(NHEAD), dim3(256), 0, stream>>>(att_b, bias_idxs, Bexp, n_off);
  wt_convert<<<dim3(QKVC / 32, CDIM / 32), dim3(32, 8), 0, stream>>>(qkv_w, wqkvT, CDIM, QKVC);
  wt_convert<<<dim3(CDIM / 32, CDIM / 32), dim3(32, 8), 0, stream>>>(proj_w, wprojT, CDIM, CDIM);
  wfrag1<<<dim3(1152), dim3(64), 0, stream>>>(fc1_w, w1f);
  wfrag2<<<dim3(1152), dim3(64), 0, stream>>>(fc2_w, w2f);

  for (int b0 = 0; b0 < 64; b0 += Bc) {
    const float* xa = x + (size_t)b0 * 1024 * CDIM;
    float* outa = out + (size_t)b0 * 1024 * CDIM;
    int M = (int)Tc;

    ln_kernel<<<dim3(M / 4), dim3(256), 0, stream>>>(xa, ln1_g, ln1_b, xn, M);
    gemm_mfma<0, 0, 1><<<dim3(QKVC / 64, M / 128), dim3(256), 0, stream>>>(
        xn, wqkvT, qkv_b, nullptr, qkv, M, QKVC, CDIM);
    attn_mfma<<<dim3(Bc * 25 * NHEAD), dim3(64), 0, stream>>>(qkv, qkv_pad, Bexp, awb);
    gemm_mfma<0, 1, 0><<<dim3(CDIM / 64, M / 128), dim3(256), 0, stream>>>(
        awb, wprojT, proj_b, xa, x1, M, CDIM, CDIM);
    conv_bn_ln_kernel<<<dim3(Bc * 64), dim3(384), 0, stream>>>(
        x1, conv_w, bn_g, bn_b, bn_m, bn_v, ln2_g, ln2_b, x2, xn);
    mlp_pc<<<dim3(M / 64), dim3(512), 0, stream>>>(
        xn, w1f, fc1_b, w2f, fc2_b, x2, outa);
  }
}

// Round 14
// 863.390 us; speedup vs baseline: 1.3168x; 1.0483x over previous
//
#include <hip/hip_runtime.h>
#include <hip/hip_bf16.h>
#include <math.h>

#define NHEAD 12
#define CDIM 384
#define QKVC 1152
#define MLPH 1536
#define SCALE 0.17677669529663687f  // 32^-0.5

typedef __attribute__((ext_vector_type(8))) short short8;
typedef __attribute__((ext_vector_type(4))) float f32x4;

static __device__ __forceinline__ unsigned short f2bf(float f) {
  union { __hip_bfloat16 b; unsigned short u; } c;
  c.b = __float2bfloat16(f);
  return c.u;
}

// fast GELU (tanh form), NaN-safe; |err| vs exact erf-GELU < ~2e-4
static __device__ __forceinline__ float gelu_f(float x) {
  float x3 = x * x * x;
  float y = 0.7978845608028654f * (x + 0.044715f * x3);
  float e = __expf(2.f * y);
  float th = 1.f - 2.f / (e + 1.f);
  return 0.5f * x * (1.f + th);
}

// ---------------- LN (wave per token, C=384) -> bf16 out ----------------
__global__ void ln_kernel(const float* __restrict__ X, const float* __restrict__ g,
                          const float* __restrict__ b, __hip_bfloat16* __restrict__ Y, int T) {
  int wid = (blockIdx.x * blockDim.x + threadIdx.x) >> 6;
  int lane = threadIdx.x & 63;
  if (wid >= T) return;
  const float* x = X + (size_t)wid * CDIM;
  float vals[6];
  float s = 0.f;
#pragma unroll
  for (int i = 0; i < 6; i++) { vals[i] = x[lane + i * 64]; s += vals[i]; }
#pragma unroll
  for (int o = 32; o > 0; o >>= 1) s += __shfl_xor(s, o);
  float m = s * (1.f / 384.f);
  float vs = 0.f;
#pragma unroll
  for (int i = 0; i < 6; i++) { float d = vals[i] - m; vs += d * d; }
#pragma unroll
  for (int o = 32; o > 0; o >>= 1) vs += __shfl_xor(vs, o);
  float rs = rsqrtf(vs * (1.f / 384.f) + 1e-5f);
  __hip_bfloat16* y = Y + (size_t)wid * CDIM;
#pragma unroll
  for (int i = 0; i < 6; i++) {
    int c = lane + i * 64;
    y[c] = __float2bfloat16((vals[i] - m) * rs * g[c] + b[c]);
  }
}

// ------------- qkv of a padded (zero) token: ln1_b @ qkv_w + qkv_b -> bf16 -------------
__global__ void pad_qkv_kernel(const float* __restrict__ lb, const float* __restrict__ Wq,
                               const float* __restrict__ bq, __hip_bfloat16* __restrict__ outp) {
  int j = blockIdx.x * blockDim.x + threadIdx.x;
  if (j >= QKVC) return;
  float s = bq[j];
  for (int c = 0; c < CDIM; c++) s += lb[c] * Wq[(size_t)c * QKVC + j];
  outp[j] = __float2bfloat16(s);
}

// ------------- expand relative-position bias to padded [12][64][64] f32 -------------
__global__ void expand_bias(const float* __restrict__ biases, const int* __restrict__ bidx,
                            float* __restrict__ Bexp, int n_off) {
  int h = blockIdx.x;
  for (int e = threadIdx.x; e < 4096; e += 256) {
    int n = e >> 6, m = e & 63;
    float v;
    if (m >= 49) v = -1e30f;
    else if (n >= 49) v = 0.f;
    else v = biases[h * n_off + bidx[n * 49 + m]];
    Bexp[h * 4096 + e] = v;
  }
}

// ---------------- weight transpose + f32->bf16 convert: W[K][N] -> Wt[N][K] ----------------
__global__ void wt_convert(const float* __restrict__ W, __hip_bfloat16* __restrict__ Wt,
                           int K, int N) {
  __shared__ float t[32][33];
  int n0 = blockIdx.x * 32, k0 = blockIdx.y * 32;
  int tx = threadIdx.x, ty = threadIdx.y;  // 32 x 8
#pragma unroll
  for (int i = 0; i < 4; i++) t[ty + i * 8][tx] = W[(size_t)(k0 + ty + i * 8) * N + n0 + tx];
  __syncthreads();
#pragma unroll
  for (int i = 0; i < 4; i++)
    Wt[(size_t)(n0 + ty + i * 8) * K + k0 + tx] = __float2bfloat16(t[tx][ty + i * 8]);
}

// -------- pack fc1_w [384][1536] into phase-1 MFMA fragment order (1m x 8n waves) --------
__global__ void wfrag1(const float* __restrict__ W, unsigned short* __restrict__ WF) {
  int f = blockIdx.x;
  int lane = threadIdx.x;
  int wn = f & 7, kk = (f >> 3) % 12, ks = f / 96;
  int n = ks * 128 + wn * 16 + (lane & 15);
  int k = kk * 32 + (lane >> 4) * 8;
  unsigned short* dst = WF + ((size_t)f * 64 + lane) * 8;
#pragma unroll
  for (int j = 0; j < 8; j++) dst[j] = f2bf(W[(size_t)(k + j) * MLPH + n]);
}

// -------- pack fc2_w [1536][384] into phase-2 MFMA fragment order (1m x 8n waves) --------
__global__ void wfrag2(const float* __restrict__ W, unsigned short* __restrict__ WF) {
  int f = blockIdx.x;
  int lane = threadIdx.x;
  int j = f % 3, wn = (f / 3) & 7, kk = (f / 24) & 3, ks = f / 96;
  int n = wn * 48 + j * 16 + (lane & 15);
  int k = ks * 128 + kk * 32 + (lane >> 4) * 8;
  unsigned short* dst = WF + ((size_t)f * 64 + lane) * 8;
#pragma unroll
  for (int jj = 0; jj < 8; jj++) dst[jj] = f2bf(W[(size_t)(k + jj) * CDIM + n]);
}

// ---------------- bf16 MFMA GEMM (128x64, R4 form): C = A @ Bt^T + bias (+res) ----------------
template <int GELU, int HAS_RES, int OUT_BF16>
__global__ __launch_bounds__(256) void gemm_mfma(
    const __hip_bfloat16* __restrict__ A, const __hip_bfloat16* __restrict__ Bt,
    const float* __restrict__ bias, const float* __restrict__ res,
    void* __restrict__ Cout, int M, int N, int K) {
  __shared__ unsigned short Al[128][72];
  __shared__ unsigned short Bl[64][72];
  int tid = threadIdx.x;
  int m0 = blockIdx.y * 128, n0 = blockIdx.x * 64;
  int wave = tid >> 6, lane = tid & 63;
  int wm = (wave >> 1) * 64, wn = (wave & 1) * 32;
  int l15 = lane & 15, l4 = lane >> 4;

  int am = tid >> 1, ak = (tid & 1) * 32;
  int bn = tid >> 2, bk = (tid & 3) * 16;
  const __hip_bfloat16* Ag = A + (size_t)(m0 + am) * K + ak;
  const __hip_bfloat16* Bg = Bt + (size_t)(n0 + bn) * K + bk;

  f32x4 acc[4][2] = {};

  for (int kt = 0; kt < K; kt += 64) {
    uint4 av0 = *(const uint4*)(Ag + kt);
    uint4 av1 = *(const uint4*)(Ag + kt + 8);
    uint4 av2 = *(const uint4*)(Ag + kt + 16);
    uint4 av3 = *(const uint4*)(Ag + kt + 24);
    uint4 bv0 = *(const uint4*)(Bg + kt);
    uint4 bv1 = *(const uint4*)(Bg + kt + 8);
    __syncthreads();
    *(uint4*)&Al[am][ak]      = av0;
    *(uint4*)&Al[am][ak + 8]  = av1;
    *(uint4*)&Al[am][ak + 16] = av2;
    *(uint4*)&Al[am][ak + 24] = av3;
    *(uint4*)&Bl[bn][bk]      = bv0;
    *(uint4*)&Bl[bn][bk + 8]  = bv1;
    __syncthreads();
#pragma unroll
    for (int kk = 0; kk < 64; kk += 32) {
      short8 af[4], bfr[2];
#pragma unroll
      for (int i = 0; i < 4; i++)
        af[i] = *(const short8*)&Al[wm + i * 16 + l15][kk + l4 * 8];
#pragma unroll
      for (int j = 0; j < 2; j++)
        bfr[j] = *(const short8*)&Bl[wn + j * 16 + l15][kk + l4 * 8];
#pragma unroll
      for (int i = 0; i < 4; i++)
#pragma unroll
        for (int j = 0; j < 2; j++)
          acc[i][j] = __builtin_amdgcn_mfma_f32_16x16x32_bf16(af[i], bfr[j], acc[i][j], 0, 0, 0);
    }
  }

#pragma unroll
  for (int i = 0; i < 4; i++) {
#pragma unroll
    for (int j = 0; j < 2; j++) {
      int n = n0 + wn + j * 16 + l15;
      float bv = bias[n];
#pragma unroll
      for (int r = 0; r < 4; r++) {
        int m = m0 + wm + i * 16 + l4 * 4 + r;
        float c = acc[i][j][r] + bv;
        if (GELU) c = gelu_f(c);
        if (HAS_RES) c += res[(size_t)m * N + n];
        if (OUT_BF16)
          ((__hip_bfloat16*)Cout)[(size_t)m * N + n] = __float2bfloat16(c);
        else
          ((float*)Cout)[(size_t)m * N + n] = c;
      }
    }
  }
}

// ---------------- fused MLP, BM=128 (R10 structure, doubled rows per block) ----------------
// 8 waves 1m x 8n (zero weight duplication). Per-block weight traffic unchanged but
// serves 2x rows -> weight bytes/token halves (R9 showed mlp time ~ 1/BM).
// LDS 133 KB -> 1 block/CU.
__global__ __launch_bounds__(512, 2) void mlp_fused(
    const __hip_bfloat16* __restrict__ XN, const unsigned short* __restrict__ W1F,
    const float* __restrict__ B1, const unsigned short* __restrict__ W2F,
    const float* __restrict__ B2, const float* __restrict__ X2,
    float* __restrict__ OUT) {
  __shared__ unsigned short XNl[128][388];   // 99328 B
  __shared__ unsigned short Hl[128][132];    // 33792 B
  int tid = threadIdx.x;
  int m0 = blockIdx.x * 128;
  int wave = tid >> 6, lane = tid & 63;
  int wn = wave;  // 8 n-groups
  int l15 = lane & 15, l4 = lane >> 4;

  {  // stage A panel 128x384 bf16, fully coalesced uint4 order (6144 uint4)
#pragma unroll
    for (int i = 0; i < 12; i++) {
      int u = tid + i * 512;
      int r = u / 48, col = (u % 48) * 8;
      *(uint4*)&XNl[r][col] =
          *(const uint4*)((const unsigned short*)XN + (size_t)(m0 + r) * 384 + col);
    }
  }

  f32x4 acc[8][3] = {};
  __syncthreads();

  for (int ks = 0; ks < 12; ks++) {
    // ---- phase 1: hacc = XN_panel @ W1 slab (wave owns 16 of 128 h-cols) ----
    f32x4 hacc[8] = {};
    const unsigned short* w1fb = W1F + ((size_t)(ks * 96 + wn)) * 512 + lane * 8;
#pragma unroll
    for (int kk = 0; kk < 12; kk++) {
      short8 bf0 = *(const short8*)(w1fb + kk * 4096);
#pragma unroll
      for (int i = 0; i < 8; i++) {
        short8 af = *(const short8*)&XNl[i * 16 + l15][kk * 32 + l4 * 8];
        hacc[i] = __builtin_amdgcn_mfma_f32_16x16x32_bf16(af, bf0, hacc[i], 0, 0, 0);
      }
    }
    float b1v = B1[ks * 128 + wn * 16 + l15];
    __syncthreads();  // prior slab's phase-2 reads of Hl done
#pragma unroll
    for (int i = 0; i < 8; i++)
#pragma unroll
      for (int r = 0; r < 4; r++) {
        float c = hacc[i][r] + b1v;
        Hl[i * 16 + l4 * 4 + r][wn * 16 + l15] = f2bf(gelu_f(c));
      }
    __syncthreads();
    // ---- phase 2: acc += Hl @ W2 slab (wave owns 48 of 384 out-cols) ----
    const unsigned short* w2fb = W2F + ((size_t)(ks * 96 + wn * 3)) * 512 + lane * 8;
#pragma unroll
    for (int kk = 0; kk < 4; kk++) {
      short8 af2[8];
#pragma unroll
      for (int i = 0; i < 8; i++)
        af2[i] = *(const short8*)&Hl[i * 16 + l15][kk * 32 + l4 * 8];
#pragma unroll
      for (int j = 0; j < 3; j++) {
        short8 bf2 = *(const short8*)(w2fb + kk * 12288 + j * 512);
#pragma unroll
        for (int i = 0; i < 8; i++)
          acc[i][j] = __builtin_amdgcn_mfma_f32_16x16x32_bf16(af2[i], bf2, acc[i][j], 0, 0, 0);
      }
    }
  }
  // ---- epilogue: + b2 + residual ----
#pragma unroll
  for (int j = 0; j < 3; j++) {
    int n = wn * 48 + j * 16 + l15;
    float bv = B2[n];
#pragma unroll
    for (int i = 0; i < 8; i++)
#pragma unroll
      for (int r = 0; r < 4; r++) {
        int m = m0 + i * 16 + l4 * 4 + r;
        OUT[(size_t)m * 384 + n] = acc[i][j][r] + bv + X2[(size_t)m * 384 + n];
      }
  }
}

// ---------------- MFMA window attention: 1 wave per (window, head) ----------------
__global__ __launch_bounds__(64) void attn_mfma(
    const __hip_bfloat16* __restrict__ qkv, const __hip_bfloat16* __restrict__ qkv_pad,
    const float* __restrict__ Bexp, __hip_bfloat16* __restrict__ aw) {
  int h = blockIdx.x % NHEAD;
  int w = blockIdx.x / NHEAD;
  int b = w / 25, wi = w % 25;
  int wh = wi / 5, wv = wi % 5;

  __shared__ unsigned short Q[64][40];
  __shared__ unsigned short K[64][40];
  __shared__ unsigned short Vt[32][72];
  __shared__ unsigned short P[64][72];

  int lane = threadIdx.x;
  int l15 = lane & 15, l4 = lane >> 4;

  {
    int t = lane;
    uint4 z = {0, 0, 0, 0};
    uint4 qv[4], kv[4];
    union { uint4 u[4]; unsigned short s[32]; } vu;
    bool use = t < 49;
    const unsigned short* src = (const unsigned short*)qkv_pad + h * 96;
    if (use) {
      int hh = wh * 7 + t / 7, ww = wv * 7 + t % 7;
      if (hh < 32 && ww < 32)
        src = (const unsigned short*)qkv + (size_t)(b * 1024 + hh * 32 + ww) * QKVC + h * 96;
    }
#pragma unroll
    for (int c = 0; c < 4; c++) {
      qv[c]   = use ? *(const uint4*)(src + c * 8)      : z;
      kv[c]   = use ? *(const uint4*)(src + 32 + c * 8) : z;
      vu.u[c] = use ? *(const uint4*)(src + 64 + c * 8) : z;
    }
#pragma unroll
    for (int c = 0; c < 4; c++) {
      *(uint4*)&Q[t][c * 8] = qv[c];
      *(uint4*)&K[t][c * 8] = kv[c];
    }
#pragma unroll
    for (int d = 0; d < 32; d++) Vt[d][t] = vu.s[d];
  }
  __syncthreads();

  f32x4 acc[4][4] = {};
  {
    short8 aq[4], bk[4];
#pragma unroll
    for (int i = 0; i < 4; i++) aq[i] = *(const short8*)&Q[i * 16 + l15][l4 * 8];
#pragma unroll
    for (int j = 0; j < 4; j++) bk[j] = *(const short8*)&K[j * 16 + l15][l4 * 8];
#pragma unroll
    for (int i = 0; i < 4; i++)
#pragma unroll
      for (int j = 0; j < 4; j++)
        acc[i][j] = __builtin_amdgcn_mfma_f32_16x16x32_bf16(aq[i], bk[j], acc[i][j], 0, 0, 0);
  }

  const float* Bh = Bexp + h * 4096;
  float rinv_[4][4];
#pragma unroll
  for (int i = 0; i < 4; i++) {
    float s[4][4];
#pragma unroll
    for (int j = 0; j < 4; j++)
#pragma unroll
      for (int r = 0; r < 4; r++) {
        int n = i * 16 + l4 * 4 + r, m = j * 16 + l15;
        s[j][r] = acc[i][j][r] * SCALE + Bh[n * 64 + m];
      }
#pragma unroll
    for (int r = 0; r < 4; r++) {
      float mx = fmaxf(fmaxf(s[0][r], s[1][r]), fmaxf(s[2][r], s[3][r]));
#pragma unroll
      for (int o = 1; o < 16; o <<= 1) mx = fmaxf(mx, __shfl_xor(mx, o));
      float p[4], sm = 0.f;
#pragma unroll
      for (int j = 0; j < 4; j++) { p[j] = __expf(s[j][r] - mx); sm += p[j]; }
#pragma unroll
      for (int o = 1; o < 16; o <<= 1) sm += __shfl_xor(sm, o);
      rinv_[i][r] = 1.f / sm;
      int n = i * 16 + l4 * 4 + r;
#pragma unroll
      for (int j = 0; j < 4; j++) P[n][j * 16 + l15] = f2bf(p[j]);
    }
  }
  __syncthreads();

  f32x4 o[4][2] = {};
#pragma unroll
  for (int ks = 0; ks < 2; ks++) {
    short8 pa[4], vb[2];
#pragma unroll
    for (int i = 0; i < 4; i++) pa[i] = *(const short8*)&P[i * 16 + l15][ks * 32 + l4 * 8];
#pragma unroll
    for (int j = 0; j < 2; j++) vb[j] = *(const short8*)&Vt[j * 16 + l15][ks * 32 + l4 * 8];
#pragma unroll
    for (int i = 0; i < 4; i++)
#pragma unroll
      for (int j = 0; j < 2; j++)
        o[i][j] = __builtin_amdgcn_mfma_f32_16x16x32_bf16(pa[i], vb[j], o[i][j], 0, 0, 0);
  }

#pragma unroll
  for (int i = 0; i < 4; i++)
#pragma unroll
    for (int r = 0; r < 4; r++) {
      int n = i * 16 + l4 * 4 + r;
      if (n < 49) {
        int hh = wh * 7 + n / 7, ww = wv * 7 + n % 7;
        if (hh < 32 && ww < 32) {
          __hip_bfloat16* dst = aw + (size_t)(b * 1024 + hh * 32 + ww) * CDIM + h * 32;
          float ri = rinv_[i][r];
#pragma unroll
          for (int j = 0; j < 2; j++)
            dst[j * 16 + l15] = __float2bfloat16(o[i][j][r] * ri);
        }
      }
    }
}

// ------- fused depthwise 3x3 conv + BN + LN2: block = (b, x, y-half), thread = channel -------
__global__ __launch_bounds__(384) void conv_bn_ln_kernel(
    const float* __restrict__ X, const float* __restrict__ W9,
    const float* __restrict__ g, const float* __restrict__ bb,
    const float* __restrict__ mm, const float* __restrict__ vv,
    const float* __restrict__ lg, const float* __restrict__ lb,
    float* __restrict__ X2, __hip_bfloat16* __restrict__ XN) {
  int nwg = gridDim.x;
  int id = blockIdx.x;
  int nid = (id & 7) * (nwg >> 3) + (id >> 3);
  int yh = nid & 1;
  int x = (nid >> 1) & 31;
  int b = nid >> 6;
  int c = threadIdx.x;

  float w[9];
#pragma unroll
  for (int i = 0; i < 9; i++) w[i] = W9[c * 9 + i];
  float bnsc = rsqrtf(vv[c] + 1e-5f) * g[c];
  float bnsh = bb[c] - mm[c] * bnsc;
  float lgc = lg[c], lbc = lb[c];

  bool xm = x > 0, xp = x < 31;
  const float* colbase = X + ((size_t)(b * 1024 + x)) * CDIM + c;

  __shared__ float part[2][6][2];
  int wv = threadIdx.x >> 6, ln = threadIdx.x & 63;

  float w0[3], w1[3], w2[3];
  int y0 = yh * 16;
  if (y0 == 0) {
    w0[0] = w0[1] = w0[2] = 0.f;
  } else {
    const float* p = colbase + (size_t)(y0 - 1) * 32 * CDIM;
    w0[0] = xm ? p[-CDIM] : 0.f; w0[1] = p[0]; w0[2] = xp ? p[CDIM] : 0.f;
  }
  {
    const float* p = colbase + (size_t)y0 * 32 * CDIM;
    w1[0] = xm ? p[-CDIM] : 0.f; w1[1] = p[0]; w1[2] = xp ? p[CDIM] : 0.f;
  }

  for (int y = y0; y < y0 + 16; y++) {
    if (y + 1 < 32) {
      const float* p = colbase + (size_t)(y + 1) * 32 * CDIM;
      w2[0] = xm ? p[-CDIM] : 0.f; w2[1] = p[0]; w2[2] = xp ? p[CDIM] : 0.f;
    } else {
      w2[0] = w2[1] = w2[2] = 0.f;
    }
    float acc = w0[0] * w[0] + w0[1] * w[1] + w0[2] * w[2]
              + w1[0] * w[3] + w1[1] * w[4] + w1[2] * w[5]
              + w2[0] * w[6] + w2[1] * w[7] + w2[2] * w[8];
    float r = acc * bnsc + bnsh;
    size_t tok = (size_t)(b * 1024 + y * 32 + x);
    X2[tok * CDIM + c] = r;

    float s1 = r, s2 = r * r;
#pragma unroll
    for (int o = 32; o > 0; o >>= 1) { s1 += __shfl_xor(s1, o); s2 += __shfl_xor(s2, o); }
    int pb = y & 1;
    if (ln == 0) { part[pb][wv][0] = s1; part[pb][wv][1] = s2; }
    __syncthreads();
    float ts1 = 0.f, ts2 = 0.f;
#pragma unroll
    for (int i = 0; i < 6; i++) { ts1 += part[pb][i][0]; ts2 += part[pb][i][1]; }
    float mean = ts1 * (1.f / 384.f);
    float var = ts2 * (1.f / 384.f) - mean * mean;
    float rstd = rsqrtf(var + 1e-5f);
    XN[tok * CDIM + c] = __float2bfloat16((r - mean) * rstd * lgc + lbc);

    w0[0] = w1[0]; w0[1] = w1[1]; w0[2] = w1[2];
    w1[0] = w2[0]; w1[1] = w2[1]; w1[2] = w2[2];
  }
}

extern "C" void kernel_launch(void* const* d_in, const int* in_sizes, int n_in,
                              void* d_out, int out_size, void* d_ws, size_t ws_size,
                              hipStream_t stream) {
  const float* x      = (const float*)d_in[0];
  const float* ln1_g  = (const float*)d_in[1];
  const float* ln1_b  = (const float*)d_in[2];
  const float* qkv_w  = (const float*)d_in[3];
  const float* qkv_b  = (const float*)d_in[4];
  const float* proj_w = (const float*)d_in[5];
  const float* proj_b = (const float*)d_in[6];
  const float* att_b  = (const float*)d_in[7];
  const float* conv_w = (const float*)d_in[8];
  const float* bn_g   = (const float*)d_in[9];
  const float* bn_b   = (const float*)d_in[10];
  const float* bn_m   = (const float*)d_in[11];
  const float* bn_v   = (const float*)d_in[12];
  const float* ln2_g  = (const float*)d_in[13];
  const float* ln2_b  = (const float*)d_in[14];
  const float* fc1_w  = (const float*)d_in[15];
  const float* fc1_b  = (const float*)d_in[16];
  const float* fc2_w  = (const float*)d_in[17];
  const float* fc2_b  = (const float*)d_in[18];
  const int* bias_idxs = (const int*)d_in[19];
  int n_off = in_sizes[7] / NHEAD;
  float* out = (float*)d_out;

  char* ws = (char*)d_ws;
  size_t off = 0;
  __hip_bfloat16* qkv_pad = (__hip_bfloat16*)(ws + off); off += QKVC * 2;
  off = (off + 255) & ~(size_t)255;
  float* Bexp = (float*)(ws + off); off += (size_t)NHEAD * 4096 * 4;
  __hip_bfloat16* wqkvT = (__hip_bfloat16*)(ws + off); off += (size_t)QKVC * CDIM * 2;
  __hip_bfloat16* wprojT = (__hip_bfloat16*)(ws + off); off += (size_t)CDIM * CDIM * 2;
  unsigned short* w1f = (unsigned short*)(ws + off); off += (size_t)MLPH * CDIM * 2;
  unsigned short* w2f = (unsigned short*)(ws + off); off += (size_t)CDIM * MLPH * 2;
  size_t HDR = (off + 255) & ~(size_t)255;

  // per-token chunk scratch (x1 aliases qkv):
  // xn bf16(768) + qkv/x1 (2304) + awb bf16(768) + x2 f32(1536) = 5376 B
  const size_t PER_TOK = 5376;
  int Bc = 64;
  while (Bc > 1 && HDR + (size_t)Bc * 1024 * PER_TOK > ws_size) Bc >>= 1;
  size_t Tc = (size_t)Bc * 1024;

  off = HDR;
  __hip_bfloat16* xn = (__hip_bfloat16*)(ws + off); off += Tc * CDIM * 2;
  __hip_bfloat16* qkv = (__hip_bfloat16*)(ws + off); off += Tc * QKVC * 2;
  float* x1 = (float*)qkv;  // alias: qkv dead after attn_mfma
  __hip_bfloat16* awb = (__hip_bfloat16*)(ws + off); off += Tc * CDIM * 2;
  float* x2 = (float*)(ws + off); off += Tc * CDIM * 4;

  pad_qkv_kernel<<<dim3(5), dim3(256), 0, stream>>>(ln1_b, qkv_w, qkv_b, qkv_pad);
  expand_bias<<<dim3(NHEAD), dim3(256), 0, stream>>>(att_b, bias_idxs, Bexp, n_off);
  wt_convert<<<dim3(QKVC / 32, CDIM / 32), dim3(32, 8), 0, stream>>>(qkv_w, wqkvT, CDIM, QKVC);
  wt_convert<<<dim3(CDIM / 32, CDIM / 32), dim3(32, 8), 0, stream>>>(proj_w, wprojT, CDIM, CDIM);
  wfrag1<<<dim3(1152), dim3(64), 0, stream>>>(fc1_w, w1f);
  wfrag2<<<dim3(1152), dim3(64), 0, stream>>>(fc2_w, w2f);

  for (int b0 = 0; b0 < 64; b0 += Bc) {
    const float* xa = x + (size_t)b0 * 1024 * CDIM;
    float* outa = out + (size_t)b0 * 1024 * CDIM;
    int M = (int)Tc;

    ln_kernel<<<dim3(M / 4), dim3(256), 0, stream>>>(xa, ln1_g, ln1_b, xn, M);
    gemm_mfma<0, 0, 1><<<dim3(QKVC / 64, M / 128), dim3(256), 0, stream>>>(
        xn, wqkvT, qkv_b, nullptr, qkv, M, QKVC, CDIM);
    attn_mfma<<<dim3(Bc * 25 * NHEAD), dim3(64), 0, stream>>>(qkv, qkv_pad, Bexp, awb);
    gemm_mfma<0, 1, 0><<<dim3(CDIM / 64, M / 128), dim3(256), 0, stream>>>(
        awb, wprojT, proj_b, xa, x1, M, CDIM, CDIM);
    conv_bn_ln_kernel<<<dim3(Bc * 64), dim3(384), 0, stream>>>(
        x1, conv_w, bn_g, bn_b, bn_m, bn_v, ln2_g, ln2_b, x2, xn);
    mlp_fused<<<dim3(M / 128), dim3(512), 0, stream>>>(
        xn, w1f, fc1_b, w2f, fc2_b, x2, outa);
  }
}

// Round 15
// 804.314 us; speedup vs baseline: 1.4135x; 1.0734x over previous
//
#include <hip/hip_runtime.h>
#include <hip/hip_bf16.h>
#include <math.h>

#define NHEAD 12
#define CDIM 384
#define QKVC 1152
#define MLPH 1536
#define SCALE 0.17677669529663687f  // 32^-0.5

typedef __attribute__((ext_vector_type(8))) short short8;
typedef __attribute__((ext_vector_type(4))) float f32x4;

static __device__ __forceinline__ unsigned short f2bf(float f) {
  union { __hip_bfloat16 b; unsigned short u; } c;
  c.b = __float2bfloat16(f);
  return c.u;
}

// fast GELU (tanh form), NaN-safe; |err| vs exact erf-GELU < ~2e-4
static __device__ __forceinline__ float gelu_f(float x) {
  float x3 = x * x * x;
  float y = 0.7978845608028654f * (x + 0.044715f * x3);
  float e = __expf(2.f * y);
  float th = 1.f - 2.f / (e + 1.f);
  return 0.5f * x * (1.f + th);
}

// ------------- qkv of a padded (zero) token: ln1_b @ qkv_w + qkv_b -> bf16 -------------
__global__ void pad_qkv_kernel(const float* __restrict__ lb, const float* __restrict__ Wq,
                               const float* __restrict__ bq, __hip_bfloat16* __restrict__ outp) {
  int j = blockIdx.x * blockDim.x + threadIdx.x;
  if (j >= QKVC) return;
  float s = bq[j];
  for (int c = 0; c < CDIM; c++) s += lb[c] * Wq[(size_t)c * QKVC + j];
  outp[j] = __float2bfloat16(s);
}

// ------------- expand relative-position bias to padded [12][64][64] f32 -------------
__global__ void expand_bias(const float* __restrict__ biases, const int* __restrict__ bidx,
                            float* __restrict__ Bexp, int n_off) {
  int h = blockIdx.x;
  for (int e = threadIdx.x; e < 4096; e += 256) {
    int n = e >> 6, m = e & 63;
    float v;
    if (m >= 49) v = -1e30f;
    else if (n >= 49) v = 0.f;
    else v = biases[h * n_off + bidx[n * 49 + m]];
    Bexp[h * 4096 + e] = v;
  }
}

// ---------------- weight transpose + f32->bf16 convert: W[K][N] -> Wt[N][K] ----------------
__global__ void wt_convert(const float* __restrict__ W, __hip_bfloat16* __restrict__ Wt,
                           int K, int N) {
  __shared__ float t[32][33];
  int n0 = blockIdx.x * 32, k0 = blockIdx.y * 32;
  int tx = threadIdx.x, ty = threadIdx.y;  // 32 x 8
#pragma unroll
  for (int i = 0; i < 4; i++) t[ty + i * 8][tx] = W[(size_t)(k0 + ty + i * 8) * N + n0 + tx];
  __syncthreads();
#pragma unroll
  for (int i = 0; i < 4; i++)
    Wt[(size_t)(n0 + ty + i * 8) * K + k0 + tx] = __float2bfloat16(t[tx][ty + i * 8]);
}

// -------- pack qkv_w [384][1152] into MFMA fragment order: f = G*12 + kk --------
// G = 16-wide col group (0..71); lane holds B[n][k]: n = G*16+(lane&15), k = kk*32+(lane>>4)*8+j
__global__ void wfragq(const float* __restrict__ W, unsigned short* __restrict__ WF) {
  int f = blockIdx.x;
  int lane = threadIdx.x;
  int kk = f % 12, G = f / 12;
  int n = G * 16 + (lane & 15);
  int k = kk * 32 + (lane >> 4) * 8;
  unsigned short* dst = WF + ((size_t)f * 64 + lane) * 8;
#pragma unroll
  for (int j = 0; j < 8; j++) dst[j] = f2bf(W[(size_t)(k + j) * QKVC + n]);
}

// -------- pack fc1_w [384][1536] into phase-1 MFMA fragment order (1m x 8n waves) --------
__global__ void wfrag1(const float* __restrict__ W, unsigned short* __restrict__ WF) {
  int f = blockIdx.x;
  int lane = threadIdx.x;
  int wn = f & 7, kk = (f >> 3) % 12, ks = f / 96;
  int n = ks * 128 + wn * 16 + (lane & 15);
  int k = kk * 32 + (lane >> 4) * 8;
  unsigned short* dst = WF + ((size_t)f * 64 + lane) * 8;
#pragma unroll
  for (int j = 0; j < 8; j++) dst[j] = f2bf(W[(size_t)(k + j) * MLPH + n]);
}

// -------- pack fc2_w [1536][384] into phase-2 MFMA fragment order (1m x 8n waves) --------
__global__ void wfrag2(const float* __restrict__ W, unsigned short* __restrict__ WF) {
  int f = blockIdx.x;
  int lane = threadIdx.x;
  int j = f % 3, wn = (f / 3) & 7, kk = (f / 24) & 3, ks = f / 96;
  int n = wn * 48 + j * 16 + (lane & 15);
  int k = ks * 128 + kk * 32 + (lane >> 4) * 8;
  unsigned short* dst = WF + ((size_t)f * 64 + lane) * 8;
#pragma unroll
  for (int jj = 0; jj < 8; jj++) dst[jj] = f2bf(W[(size_t)(k + jj) * CDIM + n]);
}

// ---------------- fused LN1 + QKV GEMM ----------------
// Grid M/64. 8 waves. Each wave LNs 8 rows of f32 X into bf16 LDS A-tile; then
// 9 rounds of 128 cols (wave owns 16 cols/round), B frags pre-packed (coalesced 1KB).
// A read ONCE from HBM; no xn round-trip; no 18x A-panel re-read.
__global__ __launch_bounds__(512) void ln_qkv(
    const float* __restrict__ X, const float* __restrict__ g, const float* __restrict__ b,
    const unsigned short* __restrict__ WQF, const float* __restrict__ BQ,
    __hip_bfloat16* __restrict__ QKV) {
  __shared__ unsigned short Al[64][388];
  int tid = threadIdx.x;
  int m0 = blockIdx.x * 64;
  int wave = tid >> 6, lane = tid & 63;
  int l15 = lane & 15, l4 = lane >> 4;

  // ---- LN stage: wave owns rows wave*8 .. wave*8+7 ----
#pragma unroll
  for (int r8 = 0; r8 < 8; r8++) {
    int row = wave * 8 + r8;
    const float* xr = X + (size_t)(m0 + row) * CDIM;
    float vals[6];
    float s = 0.f;
#pragma unroll
    for (int i = 0; i < 6; i++) { vals[i] = xr[lane + i * 64]; s += vals[i]; }
#pragma unroll
    for (int o = 32; o > 0; o >>= 1) s += __shfl_xor(s, o);
    float mean = s * (1.f / 384.f);
    float vs = 0.f;
#pragma unroll
    for (int i = 0; i < 6; i++) { float d = vals[i] - mean; vs += d * d; }
#pragma unroll
    for (int o = 32; o > 0; o >>= 1) vs += __shfl_xor(vs, o);
    float rs = rsqrtf(vs * (1.f / 384.f) + 1e-5f);
#pragma unroll
    for (int i = 0; i < 6; i++) {
      int c = lane + i * 64;
      Al[row][c] = f2bf((vals[i] - mean) * rs * g[c] + b[c]);
    }
  }
  __syncthreads();

  // ---- QKV: 9 rounds of 128 cols; wave owns group G = rd*8 + wave ----
  for (int rd = 0; rd < 9; rd++) {
    int G = rd * 8 + wave;
    f32x4 acc[4] = {};
    const unsigned short* wb = WQF + (size_t)(G * 12) * 512 + lane * 8;
#pragma unroll
    for (int kk = 0; kk < 12; kk++) {
      short8 bf = *(const short8*)(wb + kk * 512);
#pragma unroll
      for (int i = 0; i < 4; i++) {
        short8 af = *(const short8*)&Al[i * 16 + l15][kk * 32 + l4 * 8];
        acc[i] = __builtin_amdgcn_mfma_f32_16x16x32_bf16(af, bf, acc[i], 0, 0, 0);
      }
    }
    int n = G * 16 + l15;
    float bv = BQ[n];
    __hip_bfloat16* dst = QKV + (size_t)m0 * QKVC + n;
#pragma unroll
    for (int i = 0; i < 4; i++)
#pragma unroll
      for (int r = 0; r < 4; r++)
        dst[(size_t)(i * 16 + l4 * 4 + r) * QKVC] = __float2bfloat16(acc[i][r] + bv);
  }
}

// ---------------- bf16 MFMA GEMM (128x64, R4 form): C = A @ Bt^T + bias (+res) ----------------
template <int GELU, int HAS_RES, int OUT_BF16>
__global__ __launch_bounds__(256) void gemm_mfma(
    const __hip_bfloat16* __restrict__ A, const __hip_bfloat16* __restrict__ Bt,
    const float* __restrict__ bias, const float* __restrict__ res,
    void* __restrict__ Cout, int M, int N, int K) {
  __shared__ unsigned short Al[128][72];
  __shared__ unsigned short Bl[64][72];
  int tid = threadIdx.x;
  int m0 = blockIdx.y * 128, n0 = blockIdx.x * 64;
  int wave = tid >> 6, lane = tid & 63;
  int wm = (wave >> 1) * 64, wn = (wave & 1) * 32;
  int l15 = lane & 15, l4 = lane >> 4;

  int am = tid >> 1, ak = (tid & 1) * 32;
  int bn = tid >> 2, bk = (tid & 3) * 16;
  const __hip_bfloat16* Ag = A + (size_t)(m0 + am) * K + ak;
  const __hip_bfloat16* Bg = Bt + (size_t)(n0 + bn) * K + bk;

  f32x4 acc[4][2] = {};

  for (int kt = 0; kt < K; kt += 64) {
    uint4 av0 = *(const uint4*)(Ag + kt);
    uint4 av1 = *(const uint4*)(Ag + kt + 8);
    uint4 av2 = *(const uint4*)(Ag + kt + 16);
    uint4 av3 = *(const uint4*)(Ag + kt + 24);
    uint4 bv0 = *(const uint4*)(Bg + kt);
    uint4 bv1 = *(const uint4*)(Bg + kt + 8);
    __syncthreads();
    *(uint4*)&Al[am][ak]      = av0;
    *(uint4*)&Al[am][ak + 8]  = av1;
    *(uint4*)&Al[am][ak + 16] = av2;
    *(uint4*)&Al[am][ak + 24] = av3;
    *(uint4*)&Bl[bn][bk]      = bv0;
    *(uint4*)&Bl[bn][bk + 8]  = bv1;
    __syncthreads();
#pragma unroll
    for (int kk = 0; kk < 64; kk += 32) {
      short8 af[4], bfr[2];
#pragma unroll
      for (int i = 0; i < 4; i++)
        af[i] = *(const short8*)&Al[wm + i * 16 + l15][kk + l4 * 8];
#pragma unroll
      for (int j = 0; j < 2; j++)
        bfr[j] = *(const short8*)&Bl[wn + j * 16 + l15][kk + l4 * 8];
#pragma unroll
      for (int i = 0; i < 4; i++)
#pragma unroll
        for (int j = 0; j < 2; j++)
          acc[i][j] = __builtin_amdgcn_mfma_f32_16x16x32_bf16(af[i], bfr[j], acc[i][j], 0, 0, 0);
    }
  }

#pragma unroll
  for (int i = 0; i < 4; i++) {
#pragma unroll
    for (int j = 0; j < 2; j++) {
      int n = n0 + wn + j * 16 + l15;
      float bv = bias[n];
#pragma unroll
      for (int r = 0; r < 4; r++) {
        int m = m0 + wm + i * 16 + l4 * 4 + r;
        float c = acc[i][j][r] + bv;
        if (GELU) c = gelu_f(c);
        if (HAS_RES) c += res[(size_t)m * N + n];
        if (OUT_BF16)
          ((__hip_bfloat16*)Cout)[(size_t)m * N + n] = __float2bfloat16(c);
        else
          ((float*)Cout)[(size_t)m * N + n] = c;
      }
    }
  }
}

// ---------------- fused MLP (R10-verified best): 8 waves 1m x 8n, BM=64 ----------------
__global__ __launch_bounds__(512, 4) void mlp_fused(
    const __hip_bfloat16* __restrict__ XN, const unsigned short* __restrict__ W1F,
    const float* __restrict__ B1, const unsigned short* __restrict__ W2F,
    const float* __restrict__ B2, const float* __restrict__ X2,
    float* __restrict__ OUT) {
  __shared__ unsigned short XNl[64][388];
  __shared__ unsigned short Hl[64][132];
  int tid = threadIdx.x;
  int m0 = blockIdx.x * 64;
  int wave = tid >> 6, lane = tid & 63;
  int wn = wave;
  int l15 = lane & 15, l4 = lane >> 4;

  {
#pragma unroll
    for (int i = 0; i < 6; i++) {
      int u = tid + i * 512;
      int r = u / 48, col = (u % 48) * 8;
      *(uint4*)&XNl[r][col] =
          *(const uint4*)((const unsigned short*)XN + (size_t)(m0 + r) * 384 + col);
    }
  }

  f32x4 acc[4][3] = {};
  __syncthreads();

  for (int ks = 0; ks < 12; ks++) {
    f32x4 hacc[4] = {};
    const unsigned short* w1fb = W1F + ((size_t)(ks * 96 + wn)) * 512 + lane * 8;
#pragma unroll
    for (int kk = 0; kk < 12; kk++) {
      short8 bf0 = *(const short8*)(w1fb + kk * 4096);
#pragma unroll
      for (int i = 0; i < 4; i++) {
        short8 af = *(const short8*)&XNl[i * 16 + l15][kk * 32 + l4 * 8];
        hacc[i] = __builtin_amdgcn_mfma_f32_16x16x32_bf16(af, bf0, hacc[i], 0, 0, 0);
      }
    }
    float b1v = B1[ks * 128 + wn * 16 + l15];
    __syncthreads();
#pragma unroll
    for (int i = 0; i < 4; i++)
#pragma unroll
      for (int r = 0; r < 4; r++) {
        float c = hacc[i][r] + b1v;
        Hl[i * 16 + l4 * 4 + r][wn * 16 + l15] = f2bf(gelu_f(c));
      }
    __syncthreads();
    const unsigned short* w2fb = W2F + ((size_t)(ks * 96 + wn * 3)) * 512 + lane * 8;
#pragma unroll
    for (int kk = 0; kk < 4; kk++) {
      short8 af2[4];
#pragma unroll
      for (int i = 0; i < 4; i++)
        af2[i] = *(const short8*)&Hl[i * 16 + l15][kk * 32 + l4 * 8];
#pragma unroll
      for (int j = 0; j < 3; j++) {
        short8 bf2 = *(const short8*)(w2fb + kk * 12288 + j * 512);
#pragma unroll
        for (int i = 0; i < 4; i++)
          acc[i][j] = __builtin_amdgcn_mfma_f32_16x16x32_bf16(af2[i], bf2, acc[i][j], 0, 0, 0);
      }
    }
  }
#pragma unroll
  for (int j = 0; j < 3; j++) {
    int n = wn * 48 + j * 16 + l15;
    float bv = B2[n];
#pragma unroll
    for (int i = 0; i < 4; i++)
#pragma unroll
      for (int r = 0; r < 4; r++) {
        int m = m0 + i * 16 + l4 * 4 + r;
        OUT[(size_t)m * 384 + n] = acc[i][j][r] + bv + X2[(size_t)m * 384 + n];
      }
  }
}

// ---------------- MFMA window attention: 1 wave per (window, head) ----------------
__global__ __launch_bounds__(64) void attn_mfma(
    const __hip_bfloat16* __restrict__ qkv, const __hip_bfloat16* __restrict__ qkv_pad,
    const float* __restrict__ Bexp, __hip_bfloat16* __restrict__ aw) {
  int h = blockIdx.x % NHEAD;
  int w = blockIdx.x / NHEAD;
  int b = w / 25, wi = w % 25;
  int wh = wi / 5, wv = wi % 5;

  __shared__ unsigned short Q[64][40];
  __shared__ unsigned short K[64][40];
  __shared__ unsigned short Vt[32][72];
  __shared__ unsigned short P[64][72];

  int lane = threadIdx.x;
  int l15 = lane & 15, l4 = lane >> 4;

  {
    int t = lane;
    uint4 z = {0, 0, 0, 0};
    uint4 qv[4], kv[4];
    union { uint4 u[4]; unsigned short s[32]; } vu;
    bool use = t < 49;
    const unsigned short* src = (const unsigned short*)qkv_pad + h * 96;
    if (use) {
      int hh = wh * 7 + t / 7, ww = wv * 7 + t % 7;
      if (hh < 32 && ww < 32)
        src = (const unsigned short*)qkv + (size_t)(b * 1024 + hh * 32 + ww) * QKVC + h * 96;
    }
#pragma unroll
    for (int c = 0; c < 4; c++) {
      qv[c]   = use ? *(const uint4*)(src + c * 8)      : z;
      kv[c]   = use ? *(const uint4*)(src + 32 + c * 8) : z;
      vu.u[c] = use ? *(const uint4*)(src + 64 + c * 8) : z;
    }
#pragma unroll
    for (int c = 0; c < 4; c++) {
      *(uint4*)&Q[t][c * 8] = qv[c];
      *(uint4*)&K[t][c * 8] = kv[c];
    }
#pragma unroll
    for (int d = 0; d < 32; d++) Vt[d][t] = vu.s[d];
  }
  __syncthreads();

  f32x4 acc[4][4] = {};
  {
    short8 aq[4], bk[4];
#pragma unroll
    for (int i = 0; i < 4; i++) aq[i] = *(const short8*)&Q[i * 16 + l15][l4 * 8];
#pragma unroll
    for (int j = 0; j < 4; j++) bk[j] = *(const short8*)&K[j * 16 + l15][l4 * 8];
#pragma unroll
    for (int i = 0; i < 4; i++)
#pragma unroll
      for (int j = 0; j < 4; j++)
        acc[i][j] = __builtin_amdgcn_mfma_f32_16x16x32_bf16(aq[i], bk[j], acc[i][j], 0, 0, 0);
  }

  const float* Bh = Bexp + h * 4096;
  float rinv_[4][4];
#pragma unroll
  for (int i = 0; i < 4; i++) {
    float s[4][4];
#pragma unroll
    for (int j = 0; j < 4; j++)
#pragma unroll
      for (int r = 0; r < 4; r++) {
        int n = i * 16 + l4 * 4 + r, m = j * 16 + l15;
        s[j][r] = acc[i][j][r] * SCALE + Bh[n * 64 + m];
      }
#pragma unroll
    for (int r = 0; r < 4; r++) {
      float mx = fmaxf(fmaxf(s[0][r], s[1][r]), fmaxf(s[2][r], s[3][r]));
#pragma unroll
      for (int o = 1; o < 16; o <<= 1) mx = fmaxf(mx, __shfl_xor(mx, o));
      float p[4], sm = 0.f;
#pragma unroll
      for (int j = 0; j < 4; j++) { p[j] = __expf(s[j][r] - mx); sm += p[j]; }
#pragma unroll
      for (int o = 1; o < 16; o <<= 1) sm += __shfl_xor(sm, o);
      rinv_[i][r] = 1.f / sm;
      int n = i * 16 + l4 * 4 + r;
#pragma unroll
      for (int j = 0; j < 4; j++) P[n][j * 16 + l15] = f2bf(p[j]);
    }
  }
  __syncthreads();

  f32x4 o[4][2] = {};
#pragma unroll
  for (int ks = 0; ks < 2; ks++) {
    short8 pa[4], vb[2];
#pragma unroll
    for (int i = 0; i < 4; i++) pa[i] = *(const short8*)&P[i * 16 + l15][ks * 32 + l4 * 8];
#pragma unroll
    for (int j = 0; j < 2; j++) vb[j] = *(const short8*)&Vt[j * 16 + l15][ks * 32 + l4 * 8];
#pragma unroll
    for (int i = 0; i < 4; i++)
#pragma unroll
      for (int j = 0; j < 2; j++)
        o[i][j] = __builtin_amdgcn_mfma_f32_16x16x32_bf16(pa[i], vb[j], o[i][j], 0, 0, 0);
  }

#pragma unroll
  for (int i = 0; i < 4; i++)
#pragma unroll
    for (int r = 0; r < 4; r++) {
      int n = i * 16 + l4 * 4 + r;
      if (n < 49) {
        int hh = wh * 7 + n / 7, ww = wv * 7 + n % 7;
        if (hh < 32 && ww < 32) {
          __hip_bfloat16* dst = aw + (size_t)(b * 1024 + hh * 32 + ww) * CDIM + h * 32;
          float ri = rinv_[i][r];
#pragma unroll
          for (int j = 0; j < 2; j++)
            dst[j * 16 + l15] = __float2bfloat16(o[i][j][r] * ri);
        }
      }
    }
}

// ------- fused depthwise 3x3 conv + BN + LN2: block = (b, x, y-half), thread = channel -------
__global__ __launch_bounds__(384) void conv_bn_ln_kernel(
    const float* __restrict__ X, const float* __restrict__ W9,
    const float* __restrict__ g, const float* __restrict__ bb,
    const float* __restrict__ mm, const float* __restrict__ vv,
    const float* __restrict__ lg, const float* __restrict__ lb,
    float* __restrict__ X2, __hip_bfloat16* __restrict__ XN) {
  int nwg = gridDim.x;
  int id = blockIdx.x;
  int nid = (id & 7) * (nwg >> 3) + (id >> 3);
  int yh = nid & 1;
  int x = (nid >> 1) & 31;
  int b = nid >> 6;
  int c = threadIdx.x;

  float w[9];
#pragma unroll
  for (int i = 0; i < 9; i++) w[i] = W9[c * 9 + i];
  float bnsc = rsqrtf(vv[c] + 1e-5f) * g[c];
  float bnsh = bb[c] - mm[c] * bnsc;
  float lgc = lg[c], lbc = lb[c];

  bool xm = x > 0, xp = x < 31;
  const float* colbase = X + ((size_t)(b * 1024 + x)) * CDIM + c;

  __shared__ float part[2][6][2];
  int wv = threadIdx.x >> 6, ln = threadIdx.x & 63;

  float w0[3], w1[3], w2[3];
  int y0 = yh * 16;
  if (y0 == 0) {
    w0[0] = w0[1] = w0[2] = 0.f;
  } else {
    const float* p = colbase + (size_t)(y0 - 1) * 32 * CDIM;
    w0[0] = xm ? p[-CDIM] : 0.f; w0[1] = p[0]; w0[2] = xp ? p[CDIM] : 0.f;
  }
  {
    const float* p = colbase + (size_t)y0 * 32 * CDIM;
    w1[0] = xm ? p[-CDIM] : 0.f; w1[1] = p[0]; w1[2] = xp ? p[CDIM] : 0.f;
  }

  for (int y = y0; y < y0 + 16; y++) {
    if (y + 1 < 32) {
      const float* p = colbase + (size_t)(y + 1) * 32 * CDIM;
      w2[0] = xm ? p[-CDIM] : 0.f; w2[1] = p[0]; w2[2] = xp ? p[CDIM] : 0.f;
    } else {
      w2[0] = w2[1] = w2[2] = 0.f;
    }
    float acc = w0[0] * w[0] + w0[1] * w[1] + w0[2] * w[2]
              + w1[0] * w[3] + w1[1] * w[4] + w1[2] * w[5]
              + w2[0] * w[6] + w2[1] * w[7] + w2[2] * w[8];
    float r = acc * bnsc + bnsh;
    size_t tok = (size_t)(b * 1024 + y * 32 + x);
    X2[tok * CDIM + c] = r;

    float s1 = r, s2 = r * r;
#pragma unroll
    for (int o = 32; o > 0; o >>= 1) { s1 += __shfl_xor(s1, o); s2 += __shfl_xor(s2, o); }
    int pb = y & 1;
    if (ln == 0) { part[pb][wv][0] = s1; part[pb][wv][1] = s2; }
    __syncthreads();
    float ts1 = 0.f, ts2 = 0.f;
#pragma unroll
    for (int i = 0; i < 6; i++) { ts1 += part[pb][i][0]; ts2 += part[pb][i][1]; }
    float mean = ts1 * (1.f / 384.f);
    float var = ts2 * (1.f / 384.f) - mean * mean;
    float rstd = rsqrtf(var + 1e-5f);
    XN[tok * CDIM + c] = __float2bfloat16((r - mean) * rstd * lgc + lbc);

    w0[0] = w1[0]; w0[1] = w1[1]; w0[2] = w1[2];
    w1[0] = w2[0]; w1[1] = w2[1]; w1[2] = w2[2];
  }
}

extern "C" void kernel_launch(void* const* d_in, const int* in_sizes, int n_in,
                              void* d_out, int out_size, void* d_ws, size_t ws_size,
                              hipStream_t stream) {
  const float* x      = (const float*)d_in[0];
  const float* ln1_g  = (const float*)d_in[1];
  const float* ln1_b  = (const float*)d_in[2];
  const float* qkv_w  = (const float*)d_in[3];
  const float* qkv_b  = (const float*)d_in[4];
  const float* proj_w = (const float*)d_in[5];
  const float* proj_b = (const float*)d_in[6];
  const float* att_b  = (const float*)d_in[7];
  const float* conv_w = (const float*)d_in[8];
  const float* bn_g   = (const float*)d_in[9];
  const float* bn_b   = (const float*)d_in[10];
  const float* bn_m   = (const float*)d_in[11];
  const float* bn_v   = (const float*)d_in[12];
  const float* ln2_g  = (const float*)d_in[13];
  const float* ln2_b  = (const float*)d_in[14];
  const float* fc1_w  = (const float*)d_in[15];
  const float* fc1_b  = (const float*)d_in[16];
  const float* fc2_w  = (const float*)d_in[17];
  const float* fc2_b  = (const float*)d_in[18];
  const int* bias_idxs = (const int*)d_in[19];
  int n_off = in_sizes[7] / NHEAD;
  float* out = (float*)d_out;

  char* ws = (char*)d_ws;
  size_t off = 0;
  __hip_bfloat16* qkv_pad = (__hip_bfloat16*)(ws + off); off += QKVC * 2;
  off = (off + 255) & ~(size_t)255;
  float* Bexp = (float*)(ws + off); off += (size_t)NHEAD * 4096 * 4;
  unsigned short* wqf = (unsigned short*)(ws + off); off += (size_t)QKVC * CDIM * 2;
  __hip_bfloat16* wprojT = (__hip_bfloat16*)(ws + off); off += (size_t)CDIM * CDIM * 2;
  unsigned short* w1f = (unsigned short*)(ws + off); off += (size_t)MLPH * CDIM * 2;
  unsigned short* w2f = (unsigned short*)(ws + off); off += (size_t)CDIM * MLPH * 2;
  size_t HDR = (off + 255) & ~(size_t)255;

  // per-token chunk scratch (x1 aliases qkv):
  // qkv/x1 (2304) + xn bf16(768) + awb bf16(768) + x2 f32(1536) = 5376 B
  const size_t PER_TOK = 5376;
  int Bc = 64;
  while (Bc > 1 && HDR + (size_t)Bc * 1024 * PER_TOK > ws_size) Bc >>= 1;
  size_t Tc = (size_t)Bc * 1024;

  off = HDR;
  __hip_bfloat16* xn = (__hip_bfloat16*)(ws + off); off += Tc * CDIM * 2;
  __hip_bfloat16* qkv = (__hip_bfloat16*)(ws + off); off += Tc * QKVC * 2;
  float* x1 = (float*)qkv;  // alias: qkv dead after attn_mfma
  __hip_bfloat16* awb = (__hip_bfloat16*)(ws + off); off += Tc * CDIM * 2;
  float* x2 = (float*)(ws + off); off += Tc * CDIM * 4;

  pad_qkv_kernel<<<dim3(5), dim3(256), 0, stream>>>(ln1_b, qkv_w, qkv_b, qkv_pad);
  expand_bias<<<dim3(NHEAD), dim3(256), 0, stream>>>(att_b, bias_idxs, Bexp, n_off);
  wfragq<<<dim3(864), dim3(64), 0, stream>>>(qkv_w, wqf);
  wt_convert<<<dim3(CDIM / 32, CDIM / 32), dim3(32, 8), 0, stream>>>(proj_w, wprojT, CDIM, CDIM);
  wfrag1<<<dim3(1152), dim3(64), 0, stream>>>(fc1_w, w1f);
  wfrag2<<<dim3(1152), dim3(64), 0, stream>>>(fc2_w, w2f);

  for (int b0 = 0; b0 < 64; b0 += Bc) {
    const float* xa = x + (size_t)b0 * 1024 * CDIM;
    float* outa = out + (size_t)b0 * 1024 * CDIM;
    int M = (int)Tc;

    ln_qkv<<<dim3(M / 64), dim3(512), 0, stream>>>(xa, ln1_g, ln1_b, wqf, qkv_b, qkv);
    attn_mfma<<<dim3(Bc * 25 * NHEAD), dim3(64), 0, stream>>>(qkv, qkv_pad, Bexp, awb);
    gemm_mfma<0, 1, 0><<<dim3(CDIM / 64, M / 128), dim3(256), 0, stream>>>(
        awb, wprojT, proj_b, xa, x1, M, CDIM, CDIM);
    conv_bn_ln_kernel<<<dim3(Bc * 64), dim3(384), 0, stream>>>(
        x1, conv_w, bn_g, bn_b, bn_m, bn_v, ln2_g, ln2_b, x2, xn);
    mlp_fused<<<dim3(M / 64), dim3(512), 0, stream>>>(
        xn, w1f, fc1_b, w2f, fc2_b, x2, outa);
  }
}

// Round 16
// 762.423 us; speedup vs baseline: 1.4912x; 1.0549x over previous
//
#include <hip/hip_runtime.h>
#include <hip/hip_bf16.h>
#include <math.h>

#define NHEAD 12
#define CDIM 384
#define QKVC 1152
#define MLPH 1536
#define SCALE 0.17677669529663687f  // 32^-0.5

typedef __attribute__((ext_vector_type(8))) short short8;
typedef __attribute__((ext_vector_type(4))) float f32x4;

static __device__ __forceinline__ unsigned short f2bf(float f) {
  union { __hip_bfloat16 b; unsigned short u; } c;
  c.b = __float2bfloat16(f);
  return c.u;
}

// fast GELU (tanh form), NaN-safe; |err| vs exact erf-GELU < ~2e-4
static __device__ __forceinline__ float gelu_f(float x) {
  float x3 = x * x * x;
  float y = 0.7978845608028654f * (x + 0.044715f * x3);
  float e = __expf(2.f * y);
  float th = 1.f - 2.f / (e + 1.f);
  return 0.5f * x * (1.f + th);
}

// ------------- qkv of a padded (zero) token: ln1_b @ qkv_w + qkv_b -> bf16 -------------
__global__ void pad_qkv_kernel(const float* __restrict__ lb, const float* __restrict__ Wq,
                               const float* __restrict__ bq, __hip_bfloat16* __restrict__ outp) {
  int j = blockIdx.x * blockDim.x + threadIdx.x;
  if (j >= QKVC) return;
  float s = bq[j];
  for (int c = 0; c < CDIM; c++) s += lb[c] * Wq[(size_t)c * QKVC + j];
  outp[j] = __float2bfloat16(s);
}

// ------------- expand relative-position bias to padded [12][64][64] f32 -------------
__global__ void expand_bias(const float* __restrict__ biases, const int* __restrict__ bidx,
                            float* __restrict__ Bexp, int n_off) {
  int h = blockIdx.x;
  for (int e = threadIdx.x; e < 4096; e += 256) {
    int n = e >> 6, m = e & 63;
    float v;
    if (m >= 49) v = -1e30f;
    else if (n >= 49) v = 0.f;
    else v = biases[h * n_off + bidx[n * 49 + m]];
    Bexp[h * 4096 + e] = v;
  }
}

// ---------------- weight transpose + f32->bf16 convert: W[K][N] -> Wt[N][K] ----------------
__global__ void wt_convert(const float* __restrict__ W, __hip_bfloat16* __restrict__ Wt,
                           int K, int N) {
  __shared__ float t[32][33];
  int n0 = blockIdx.x * 32, k0 = blockIdx.y * 32;
  int tx = threadIdx.x, ty = threadIdx.y;  // 32 x 8
#pragma unroll
  for (int i = 0; i < 4; i++) t[ty + i * 8][tx] = W[(size_t)(k0 + ty + i * 8) * N + n0 + tx];
  __syncthreads();
#pragma unroll
  for (int i = 0; i < 4; i++)
    Wt[(size_t)(n0 + ty + i * 8) * K + k0 + tx] = __float2bfloat16(t[tx][ty + i * 8]);
}

// -------- pack qkv_w [384][1152] into MFMA fragment order: f = G*12 + kk --------
__global__ void wfragq(const float* __restrict__ W, unsigned short* __restrict__ WF) {
  int f = blockIdx.x;
  int lane = threadIdx.x;
  int kk = f % 12, G = f / 12;
  int n = G * 16 + (lane & 15);
  int k = kk * 32 + (lane >> 4) * 8;
  unsigned short* dst = WF + ((size_t)f * 64 + lane) * 8;
#pragma unroll
  for (int j = 0; j < 8; j++) dst[j] = f2bf(W[(size_t)(k + j) * QKVC + n]);
}

// -------- pack fc1_w [384][1536] into phase-1 MFMA fragment order (1m x 8n waves) --------
__global__ void wfrag1(const float* __restrict__ W, unsigned short* __restrict__ WF) {
  int f = blockIdx.x;
  int lane = threadIdx.x;
  int wn = f & 7, kk = (f >> 3) % 12, ks = f / 96;
  int n = ks * 128 + wn * 16 + (lane & 15);
  int k = kk * 32 + (lane >> 4) * 8;
  unsigned short* dst = WF + ((size_t)f * 64 + lane) * 8;
#pragma unroll
  for (int j = 0; j < 8; j++) dst[j] = f2bf(W[(size_t)(k + j) * MLPH + n]);
}

// -------- pack fc2_w [1536][384] into phase-2 MFMA fragment order (1m x 8n waves) --------
__global__ void wfrag2(const float* __restrict__ W, unsigned short* __restrict__ WF) {
  int f = blockIdx.x;
  int lane = threadIdx.x;
  int j = f % 3, wn = (f / 3) & 7, kk = (f / 24) & 3, ks = f / 96;
  int n = wn * 48 + j * 16 + (lane & 15);
  int k = ks * 128 + kk * 32 + (lane >> 4) * 8;
  unsigned short* dst = WF + ((size_t)f * 64 + lane) * 8;
#pragma unroll
  for (int jj = 0; jj < 8; jj++) dst[jj] = f2bf(W[(size_t)(k + jj) * CDIM + n]);
}

// ---------------- fused LN1 + QKV GEMM ----------------
__global__ __launch_bounds__(512) void ln_qkv(
    const float* __restrict__ X, const float* __restrict__ g, const float* __restrict__ b,
    const unsigned short* __restrict__ WQF, const float* __restrict__ BQ,
    __hip_bfloat16* __restrict__ QKV) {
  __shared__ unsigned short Al[64][388];
  int tid = threadIdx.x;
  int m0 = blockIdx.x * 64;
  int wave = tid >> 6, lane = tid & 63;
  int l15 = lane & 15, l4 = lane >> 4;

#pragma unroll
  for (int r8 = 0; r8 < 8; r8++) {
    int row = wave * 8 + r8;
    const float* xr = X + (size_t)(m0 + row) * CDIM;
    float vals[6];
    float s = 0.f;
#pragma unroll
    for (int i = 0; i < 6; i++) { vals[i] = xr[lane + i * 64]; s += vals[i]; }
#pragma unroll
    for (int o = 32; o > 0; o >>= 1) s += __shfl_xor(s, o);
    float mean = s * (1.f / 384.f);
    float vs = 0.f;
#pragma unroll
    for (int i = 0; i < 6; i++) { float d = vals[i] - mean; vs += d * d; }
#pragma unroll
    for (int o = 32; o > 0; o >>= 1) vs += __shfl_xor(vs, o);
    float rs = rsqrtf(vs * (1.f / 384.f) + 1e-5f);
#pragma unroll
    for (int i = 0; i < 6; i++) {
      int c = lane + i * 64;
      Al[row][c] = f2bf((vals[i] - mean) * rs * g[c] + b[c]);
    }
  }
  __syncthreads();

  for (int rd = 0; rd < 9; rd++) {
    int G = rd * 8 + wave;
    f32x4 acc[4] = {};
    const unsigned short* wb = WQF + (size_t)(G * 12) * 512 + lane * 8;
#pragma unroll
    for (int kk = 0; kk < 12; kk++) {
      short8 bf = *(const short8*)(wb + kk * 512);
#pragma unroll
      for (int i = 0; i < 4; i++) {
        short8 af = *(const short8*)&Al[i * 16 + l15][kk * 32 + l4 * 8];
        acc[i] = __builtin_amdgcn_mfma_f32_16x16x32_bf16(af, bf, acc[i], 0, 0, 0);
      }
    }
    int n = G * 16 + l15;
    float bv = BQ[n];
    __hip_bfloat16* dst = QKV + (size_t)m0 * QKVC + n;
#pragma unroll
    for (int i = 0; i < 4; i++)
#pragma unroll
      for (int r = 0; r < 4; r++)
        dst[(size_t)(i * 16 + l4 * 4 + r) * QKVC] = __float2bfloat16(acc[i][r] + bv);
  }
}

// ---------------- bf16 MFMA GEMM (128x64, R4 form): C = A @ Bt^T + bias (+res f32) ----------------
template <int GELU, int HAS_RES, int OUT_BF16>
__global__ __launch_bounds__(256) void gemm_mfma(
    const __hip_bfloat16* __restrict__ A, const __hip_bfloat16* __restrict__ Bt,
    const float* __restrict__ bias, const float* __restrict__ res,
    void* __restrict__ Cout, int M, int N, int K) {
  __shared__ unsigned short Al[128][72];
  __shared__ unsigned short Bl[64][72];
  int tid = threadIdx.x;
  int m0 = blockIdx.y * 128, n0 = blockIdx.x * 64;
  int wave = tid >> 6, lane = tid & 63;
  int wm = (wave >> 1) * 64, wn = (wave & 1) * 32;
  int l15 = lane & 15, l4 = lane >> 4;

  int am = tid >> 1, ak = (tid & 1) * 32;
  int bn = tid >> 2, bk = (tid & 3) * 16;
  const __hip_bfloat16* Ag = A + (size_t)(m0 + am) * K + ak;
  const __hip_bfloat16* Bg = Bt + (size_t)(n0 + bn) * K + bk;

  f32x4 acc[4][2] = {};

  for (int kt = 0; kt < K; kt += 64) {
    uint4 av0 = *(const uint4*)(Ag + kt);
    uint4 av1 = *(const uint4*)(Ag + kt + 8);
    uint4 av2 = *(const uint4*)(Ag + kt + 16);
    uint4 av3 = *(const uint4*)(Ag + kt + 24);
    uint4 bv0 = *(const uint4*)(Bg + kt);
    uint4 bv1 = *(const uint4*)(Bg + kt + 8);
    __syncthreads();
    *(uint4*)&Al[am][ak]      = av0;
    *(uint4*)&Al[am][ak + 8]  = av1;
    *(uint4*)&Al[am][ak + 16] = av2;
    *(uint4*)&Al[am][ak + 24] = av3;
    *(uint4*)&Bl[bn][bk]      = bv0;
    *(uint4*)&Bl[bn][bk + 8]  = bv1;
    __syncthreads();
#pragma unroll
    for (int kk = 0; kk < 64; kk += 32) {
      short8 af[4], bfr[2];
#pragma unroll
      for (int i = 0; i < 4; i++)
        af[i] = *(const short8*)&Al[wm + i * 16 + l15][kk + l4 * 8];
#pragma unroll
      for (int j = 0; j < 2; j++)
        bfr[j] = *(const short8*)&Bl[wn + j * 16 + l15][kk + l4 * 8];
#pragma unroll
      for (int i = 0; i < 4; i++)
#pragma unroll
        for (int j = 0; j < 2; j++)
          acc[i][j] = __builtin_amdgcn_mfma_f32_16x16x32_bf16(af[i], bfr[j], acc[i][j], 0, 0, 0);
    }
  }

#pragma unroll
  for (int i = 0; i < 4; i++) {
#pragma unroll
    for (int j = 0; j < 2; j++) {
      int n = n0 + wn + j * 16 + l15;
      float bv = bias[n];
#pragma unroll
      for (int r = 0; r < 4; r++) {
        int m = m0 + wm + i * 16 + l4 * 4 + r;
        float c = acc[i][j][r] + bv;
        if (GELU) c = gelu_f(c);
        if (HAS_RES) c += res[(size_t)m * N + n];
        if (OUT_BF16)
          ((__hip_bfloat16*)Cout)[(size_t)m * N + n] = __float2bfloat16(c);
        else
          ((float*)Cout)[(size_t)m * N + n] = c;
      }
    }
  }
}

// ---------------- fused MLP (R10 best): 8 waves 1m x 8n, BM=64; X2 residual bf16 ----------------
__global__ __launch_bounds__(512, 4) void mlp_fused(
    const __hip_bfloat16* __restrict__ XN, const unsigned short* __restrict__ W1F,
    const float* __restrict__ B1, const unsigned short* __restrict__ W2F,
    const float* __restrict__ B2, const __hip_bfloat16* __restrict__ X2,
    float* __restrict__ OUT) {
  __shared__ unsigned short XNl[64][388];
  __shared__ unsigned short Hl[64][132];
  int tid = threadIdx.x;
  int m0 = blockIdx.x * 64;
  int wave = tid >> 6, lane = tid & 63;
  int wn = wave;
  int l15 = lane & 15, l4 = lane >> 4;

  {
#pragma unroll
    for (int i = 0; i < 6; i++) {
      int u = tid + i * 512;
      int r = u / 48, col = (u % 48) * 8;
      *(uint4*)&XNl[r][col] =
          *(const uint4*)((const unsigned short*)XN + (size_t)(m0 + r) * 384 + col);
    }
  }

  f32x4 acc[4][3] = {};
  __syncthreads();

  for (int ks = 0; ks < 12; ks++) {
    f32x4 hacc[4] = {};
    const unsigned short* w1fb = W1F + ((size_t)(ks * 96 + wn)) * 512 + lane * 8;
#pragma unroll
    for (int kk = 0; kk < 12; kk++) {
      short8 bf0 = *(const short8*)(w1fb + kk * 4096);
#pragma unroll
      for (int i = 0; i < 4; i++) {
        short8 af = *(const short8*)&XNl[i * 16 + l15][kk * 32 + l4 * 8];
        hacc[i] = __builtin_amdgcn_mfma_f32_16x16x32_bf16(af, bf0, hacc[i], 0, 0, 0);
      }
    }
    float b1v = B1[ks * 128 + wn * 16 + l15];
    __syncthreads();
#pragma unroll
    for (int i = 0; i < 4; i++)
#pragma unroll
      for (int r = 0; r < 4; r++) {
        float c = hacc[i][r] + b1v;
        Hl[i * 16 + l4 * 4 + r][wn * 16 + l15] = f2bf(gelu_f(c));
      }
    __syncthreads();
    const unsigned short* w2fb = W2F + ((size_t)(ks * 96 + wn * 3)) * 512 + lane * 8;
#pragma unroll
    for (int kk = 0; kk < 4; kk++) {
      short8 af2[4];
#pragma unroll
      for (int i = 0; i < 4; i++)
        af2[i] = *(const short8*)&Hl[i * 16 + l15][kk * 32 + l4 * 8];
#pragma unroll
      for (int j = 0; j < 3; j++) {
        short8 bf2 = *(const short8*)(w2fb + kk * 12288 + j * 512);
#pragma unroll
        for (int i = 0; i < 4; i++)
          acc[i][j] = __builtin_amdgcn_mfma_f32_16x16x32_bf16(af2[i], bf2, acc[i][j], 0, 0, 0);
      }
    }
  }
#pragma unroll
  for (int j = 0; j < 3; j++) {
    int n = wn * 48 + j * 16 + l15;
    float bv = B2[n];
#pragma unroll
    for (int i = 0; i < 4; i++)
#pragma unroll
      for (int r = 0; r < 4; r++) {
        int m = m0 + i * 16 + l4 * 4 + r;
        OUT[(size_t)m * 384 + n] =
            acc[i][j][r] + bv + __bfloat162float(X2[(size_t)m * 384 + n]);
      }
  }
}

// ---------------- MFMA window attention: 1 wave per (window, head) ----------------
__global__ __launch_bounds__(64) void attn_mfma(
    const __hip_bfloat16* __restrict__ qkv, const __hip_bfloat16* __restrict__ qkv_pad,
    const float* __restrict__ Bexp, __hip_bfloat16* __restrict__ aw) {
  int h = blockIdx.x % NHEAD;
  int w = blockIdx.x / NHEAD;
  int b = w / 25, wi = w % 25;
  int wh = wi / 5, wv = wi % 5;

  __shared__ unsigned short Q[64][40];
  __shared__ unsigned short K[64][40];
  __shared__ unsigned short Vt[32][72];
  __shared__ unsigned short P[64][72];

  int lane = threadIdx.x;
  int l15 = lane & 15, l4 = lane >> 4;

  {
    int t = lane;
    uint4 z = {0, 0, 0, 0};
    uint4 qv[4], kv[4];
    union { uint4 u[4]; unsigned short s[32]; } vu;
    bool use = t < 49;
    const unsigned short* src = (const unsigned short*)qkv_pad + h * 96;
    if (use) {
      int hh = wh * 7 + t / 7, ww = wv * 7 + t % 7;
      if (hh < 32 && ww < 32)
        src = (const unsigned short*)qkv + (size_t)(b * 1024 + hh * 32 + ww) * QKVC + h * 96;
    }
#pragma unroll
    for (int c = 0; c < 4; c++) {
      qv[c]   = use ? *(const uint4*)(src + c * 8)      : z;
      kv[c]   = use ? *(const uint4*)(src + 32 + c * 8) : z;
      vu.u[c] = use ? *(const uint4*)(src + 64 + c * 8) : z;
    }
#pragma unroll
    for (int c = 0; c < 4; c++) {
      *(uint4*)&Q[t][c * 8] = qv[c];
      *(uint4*)&K[t][c * 8] = kv[c];
    }
#pragma unroll
    for (int d = 0; d < 32; d++) Vt[d][t] = vu.s[d];
  }
  __syncthreads();

  f32x4 acc[4][4] = {};
  {
    short8 aq[4], bk[4];
#pragma unroll
    for (int i = 0; i < 4; i++) aq[i] = *(const short8*)&Q[i * 16 + l15][l4 * 8];
#pragma unroll
    for (int j = 0; j < 4; j++) bk[j] = *(const short8*)&K[j * 16 + l15][l4 * 8];
#pragma unroll
    for (int i = 0; i < 4; i++)
#pragma unroll
      for (int j = 0; j < 4; j++)
        acc[i][j] = __builtin_amdgcn_mfma_f32_16x16x32_bf16(aq[i], bk[j], acc[i][j], 0, 0, 0);
  }

  const float* Bh = Bexp + h * 4096;
  float rinv_[4][4];
#pragma unroll
  for (int i = 0; i < 4; i++) {
    float s[4][4];
#pragma unroll
    for (int j = 0; j < 4; j++)
#pragma unroll
      for (int r = 0; r < 4; r++) {
        int n = i * 16 + l4 * 4 + r, m = j * 16 + l15;
        s[j][r] = acc[i][j][r] * SCALE + Bh[n * 64 + m];
      }
#pragma unroll
    for (int r = 0; r < 4; r++) {
      float mx = fmaxf(fmaxf(s[0][r], s[1][r]), fmaxf(s[2][r], s[3][r]));
#pragma unroll
      for (int o = 1; o < 16; o <<= 1) mx = fmaxf(mx, __shfl_xor(mx, o));
      float p[4], sm = 0.f;
#pragma unroll
      for (int j = 0; j < 4; j++) { p[j] = __expf(s[j][r] - mx); sm += p[j]; }
#pragma unroll
      for (int o = 1; o < 16; o <<= 1) sm += __shfl_xor(sm, o);
      rinv_[i][r] = 1.f / sm;
      int n = i * 16 + l4 * 4 + r;
#pragma unroll
      for (int j = 0; j < 4; j++) P[n][j * 16 + l15] = f2bf(p[j]);
    }
  }
  __syncthreads();

  f32x4 o[4][2] = {};
#pragma unroll
  for (int ks = 0; ks < 2; ks++) {
    short8 pa[4], vb[2];
#pragma unroll
    for (int i = 0; i < 4; i++) pa[i] = *(const short8*)&P[i * 16 + l15][ks * 32 + l4 * 8];
#pragma unroll
    for (int j = 0; j < 2; j++) vb[j] = *(const short8*)&Vt[j * 16 + l15][ks * 32 + l4 * 8];
#pragma unroll
    for (int i = 0; i < 4; i++)
#pragma unroll
      for (int j = 0; j < 2; j++)
        o[i][j] = __builtin_amdgcn_mfma_f32_16x16x32_bf16(pa[i], vb[j], o[i][j], 0, 0, 0);
  }

#pragma unroll
  for (int i = 0; i < 4; i++)
#pragma unroll
    for (int r = 0; r < 4; r++) {
      int n = i * 16 + l4 * 4 + r;
      if (n < 49) {
        int hh = wh * 7 + n / 7, ww = wv * 7 + n % 7;
        if (hh < 32 && ww < 32) {
          __hip_bfloat16* dst = aw + (size_t)(b * 1024 + hh * 32 + ww) * CDIM + h * 32;
          float ri = rinv_[i][r];
#pragma unroll
          for (int j = 0; j < 2; j++)
            dst[j * 16 + l15] = __float2bfloat16(o[i][j][r] * ri);
        }
      }
    }
}

// ------- fused depthwise 3x3 conv + BN + LN2 (x1 bf16 in, x2 bf16 out) -------
__global__ __launch_bounds__(384) void conv_bn_ln_kernel(
    const __hip_bfloat16* __restrict__ X, const float* __restrict__ W9,
    const float* __restrict__ g, const float* __restrict__ bb,
    const float* __restrict__ mm, const float* __restrict__ vv,
    const float* __restrict__ lg, const float* __restrict__ lb,
    __hip_bfloat16* __restrict__ X2, __hip_bfloat16* __restrict__ XN) {
  int nwg = gridDim.x;
  int id = blockIdx.x;
  int nid = (id & 7) * (nwg >> 3) + (id >> 3);
  int yh = nid & 1;
  int x = (nid >> 1) & 31;
  int b = nid >> 6;
  int c = threadIdx.x;

  float w[9];
#pragma unroll
  for (int i = 0; i < 9; i++) w[i] = W9[c * 9 + i];
  float bnsc = rsqrtf(vv[c] + 1e-5f) * g[c];
  float bnsh = bb[c] - mm[c] * bnsc;
  float lgc = lg[c], lbc = lb[c];

  bool xm = x > 0, xp = x < 31;
  const __hip_bfloat16* colbase = X + ((size_t)(b * 1024 + x)) * CDIM + c;

  __shared__ float part[2][6][2];
  int wv = threadIdx.x >> 6, ln = threadIdx.x & 63;

  float w0[3], w1[3], w2[3];
  int y0 = yh * 16;
  if (y0 == 0) {
    w0[0] = w0[1] = w0[2] = 0.f;
  } else {
    const __hip_bfloat16* p = colbase + (size_t)(y0 - 1) * 32 * CDIM;
    w0[0] = xm ? __bfloat162float(p[-CDIM]) : 0.f;
    w0[1] = __bfloat162float(p[0]);
    w0[2] = xp ? __bfloat162float(p[CDIM]) : 0.f;
  }
  {
    const __hip_bfloat16* p = colbase + (size_t)y0 * 32 * CDIM;
    w1[0] = xm ? __bfloat162float(p[-CDIM]) : 0.f;
    w1[1] = __bfloat162float(p[0]);
    w1[2] = xp ? __bfloat162float(p[CDIM]) : 0.f;
  }

  for (int y = y0; y < y0 + 16; y++) {
    if (y + 1 < 32) {
      const __hip_bfloat16* p = colbase + (size_t)(y + 1) * 32 * CDIM;
      w2[0] = xm ? __bfloat162float(p[-CDIM]) : 0.f;
      w2[1] = __bfloat162float(p[0]);
      w2[2] = xp ? __bfloat162float(p[CDIM]) : 0.f;
    } else {
      w2[0] = w2[1] = w2[2] = 0.f;
    }
    float acc = w0[0] * w[0] + w0[1] * w[1] + w0[2] * w[2]
              + w1[0] * w[3] + w1[1] * w[4] + w1[2] * w[5]
              + w2[0] * w[6] + w2[1] * w[7] + w2[2] * w[8];
    float r = acc * bnsc + bnsh;
    size_t tok = (size_t)(b * 1024 + y * 32 + x);
    X2[tok * CDIM + c] = __float2bfloat16(r);

    float s1 = r, s2 = r * r;
#pragma unroll
    for (int o = 32; o > 0; o >>= 1) { s1 += __shfl_xor(s1, o); s2 += __shfl_xor(s2, o); }
    int pb = y & 1;
    if (ln == 0) { part[pb][wv][0] = s1; part[pb][wv][1] = s2; }
    __syncthreads();
    float ts1 = 0.f, ts2 = 0.f;
#pragma unroll
    for (int i = 0; i < 6; i++) { ts1 += part[pb][i][0]; ts2 += part[pb][i][1]; }
    float mean = ts1 * (1.f / 384.f);
    float var = ts2 * (1.f / 384.f) - mean * mean;
    float rstd = rsqrtf(var + 1e-5f);
    XN[tok * CDIM + c] = __float2bfloat16((r - mean) * rstd * lgc + lbc);

    w0[0] = w1[0]; w0[1] = w1[1]; w0[2] = w1[2];
    w1[0] = w2[0]; w1[1] = w2[1]; w1[2] = w2[2];
  }
}

extern "C" void kernel_launch(void* const* d_in, const int* in_sizes, int n_in,
                              void* d_out, int out_size, void* d_ws, size_t ws_size,
                              hipStream_t stream) {
  const float* x      = (const float*)d_in[0];
  const float* ln1_g  = (const float*)d_in[1];
  const float* ln1_b  = (const float*)d_in[2];
  const float* qkv_w  = (const float*)d_in[3];
  const float* qkv_b  = (const float*)d_in[4];
  const float* proj_w = (const float*)d_in[5];
  const float* proj_b = (const float*)d_in[6];
  const float* att_b  = (const float*)d_in[7];
  const float* conv_w = (const float*)d_in[8];
  const float* bn_g   = (const float*)d_in[9];
  const float* bn_b   = (const float*)d_in[10];
  const float* bn_m   = (const float*)d_in[11];
  const float* bn_v   = (const float*)d_in[12];
  const float* ln2_g  = (const float*)d_in[13];
  const float* ln2_b  = (const float*)d_in[14];
  const float* fc1_w  = (const float*)d_in[15];
  const float* fc1_b  = (const float*)d_in[16];
  const float* fc2_w  = (const float*)d_in[17];
  const float* fc2_b  = (const float*)d_in[18];
  const int* bias_idxs = (const int*)d_in[19];
  int n_off = in_sizes[7] / NHEAD;
  float* out = (float*)d_out;

  char* ws = (char*)d_ws;
  size_t off = 0;
  __hip_bfloat16* qkv_pad = (__hip_bfloat16*)(ws + off); off += QKVC * 2;
  off = (off + 255) & ~(size_t)255;
  float* Bexp = (float*)(ws + off); off += (size_t)NHEAD * 4096 * 4;
  unsigned short* wqf = (unsigned short*)(ws + off); off += (size_t)QKVC * CDIM * 2;
  __hip_bfloat16* wprojT = (__hip_bfloat16*)(ws + off); off += (size_t)CDIM * CDIM * 2;
  unsigned short* w1f = (unsigned short*)(ws + off); off += (size_t)MLPH * CDIM * 2;
  unsigned short* w2f = (unsigned short*)(ws + off); off += (size_t)CDIM * MLPH * 2;
  size_t HDR = (off + 255) & ~(size_t)255;

  // per-token chunk scratch (x1 aliases qkv, both bf16 now):
  // qkv/x1 (2304) + xn bf16(768) + awb bf16(768) + x2 bf16(768) = 4608 B
  const size_t PER_TOK = 4608;
  int Bc = 64;
  while (Bc > 1 && HDR + (size_t)Bc * 1024 * PER_TOK > ws_size) Bc >>= 1;
  size_t Tc = (size_t)Bc * 1024;

  off = HDR;
  __hip_bfloat16* xn = (__hip_bfloat16*)(ws + off); off += Tc * CDIM * 2;
  __hip_bfloat16* qkv = (__hip_bfloat16*)(ws + off); off += Tc * QKVC * 2;
  __hip_bfloat16* x1 = qkv;  // alias: qkv dead after attn_mfma
  __hip_bfloat16* awb = (__hip_bfloat16*)(ws + off); off += Tc * CDIM * 2;
  __hip_bfloat16* x2 = (__hip_bfloat16*)(ws + off); off += Tc * CDIM * 2;

  pad_qkv_kernel<<<dim3(5), dim3(256), 0, stream>>>(ln1_b, qkv_w, qkv_b, qkv_pad);
  expand_bias<<<dim3(NHEAD), dim3(256), 0, stream>>>(att_b, bias_idxs, Bexp, n_off);
  wfragq<<<dim3(864), dim3(64), 0, stream>>>(qkv_w, wqf);
  wt_convert<<<dim3(CDIM / 32, CDIM / 32), dim3(32, 8), 0, stream>>>(proj_w, wprojT, CDIM, CDIM);
  wfrag1<<<dim3(1152), dim3(64), 0, stream>>>(fc1_w, w1f);
  wfrag2<<<dim3(1152), dim3(64), 0, stream>>>(fc2_w, w2f);

  for (int b0 = 0; b0 < 64; b0 += Bc) {
    const float* xa = x + (size_t)b0 * 1024 * CDIM;
    float* outa = out + (size_t)b0 * 1024 * CDIM;
    int M = (int)Tc;

    ln_qkv<<<dim3(M / 64), dim3(512), 0, stream>>>(xa, ln1_g, ln1_b, wqf, qkv_b, qkv);
    attn_mfma<<<dim3(Bc * 25 * NHEAD), dim3(64), 0, stream>>>(qkv, qkv_pad, Bexp, awb);
    gemm_mfma<0, 1, 1><<<dim3(CDIM / 64, M / 128), dim3(256), 0, stream>>>(
        awb, wprojT, proj_b, xa, x1, M, CDIM, CDIM);
    conv_bn_ln_kernel<<<dim3(Bc * 64), dim3(384), 0, stream>>>(
        x1, conv_w, bn_g, bn_b, bn_m, bn_v, ln2_g, ln2_b, x2, xn);
    mlp_fused<<<dim3(M / 64), dim3(512), 0, stream>>>(
        xn, w1f, fc1_b, w2f, fc2_b, x2, outa);
  }
}

// Round 17
// 759.860 us; speedup vs baseline: 1.4962x; 1.0034x over previous
//
#include <hip/hip_runtime.h>
#include <hip/hip_bf16.h>
#include <math.h>

#define NHEAD 12
#define CDIM 384
#define QKVC 1152
#define MLPH 1536
#define SCALE 0.17677669529663687f  // 32^-0.5

typedef __attribute__((ext_vector_type(8))) short short8;
typedef __attribute__((ext_vector_type(4))) float f32x4;

static __device__ __forceinline__ unsigned short f2bf(float f) {
  union { __hip_bfloat16 b; unsigned short u; } c;
  c.b = __float2bfloat16(f);
  return c.u;
}

// tanh-form GELU in sigmoid representation: x*sigma(2y), y=0.79788456(x+0.044715x^3).
// Mathematically identical to 0.5x(1+tanh(y)); 5 VALU + 2 trans. NaN-safe.
static __device__ __forceinline__ float gelu_f(float x) {
  float x2 = x * x;
  float t = __builtin_fmaf(0.044715f * x2, x, x);
  float e = __expf(-1.5957691216057308f * t);
  return x / (1.f + e);
}

// ------------- qkv of a padded (zero) token: ln1_b @ qkv_w + qkv_b -> bf16 -------------
__global__ void pad_qkv_kernel(const float* __restrict__ lb, const float* __restrict__ Wq,
                               const float* __restrict__ bq, __hip_bfloat16* __restrict__ outp) {
  int j = blockIdx.x * blockDim.x + threadIdx.x;
  if (j >= QKVC) return;
  float s = bq[j];
  for (int c = 0; c < CDIM; c++) s += lb[c] * Wq[(size_t)c * QKVC + j];
  outp[j] = __float2bfloat16(s);
}

// ------------- expand relative-position bias to padded [12][64][64] f32 -------------
__global__ void expand_bias(const float* __restrict__ biases, const int* __restrict__ bidx,
                            float* __restrict__ Bexp, int n_off) {
  int h = blockIdx.x;
  for (int e = threadIdx.x; e < 4096; e += 256) {
    int n = e >> 6, m = e & 63;
    float v;
    if (m >= 49) v = -1e30f;
    else if (n >= 49) v = 0.f;
    else v = biases[h * n_off + bidx[n * 49 + m]];
    Bexp[h * 4096 + e] = v;
  }
}

// -------- pack qkv_w [384][1152] into MFMA fragment order: f = G*12 + kk --------
__global__ void wfragq(const float* __restrict__ W, unsigned short* __restrict__ WF) {
  int f = blockIdx.x;
  int lane = threadIdx.x;
  int kk = f % 12, G = f / 12;
  int n = G * 16 + (lane & 15);
  int k = kk * 32 + (lane >> 4) * 8;
  unsigned short* dst = WF + ((size_t)f * 64 + lane) * 8;
#pragma unroll
  for (int j = 0; j < 8; j++) dst[j] = f2bf(W[(size_t)(k + j) * QKVC + n]);
}

// -------- pack proj_w [384][384] into MFMA fragment order: f = G*12 + kk (G=0..23) --------
__global__ void wfragp(const float* __restrict__ W, unsigned short* __restrict__ WF) {
  int f = blockIdx.x;
  int lane = threadIdx.x;
  int kk = f % 12, G = f / 12;
  int n = G * 16 + (lane & 15);
  int k = kk * 32 + (lane >> 4) * 8;
  unsigned short* dst = WF + ((size_t)f * 64 + lane) * 8;
#pragma unroll
  for (int j = 0; j < 8; j++) dst[j] = f2bf(W[(size_t)(k + j) * CDIM + n]);
}

// -------- pack fc1_w [384][1536] into phase-1 MFMA fragment order (1m x 8n waves) --------
__global__ void wfrag1(const float* __restrict__ W, unsigned short* __restrict__ WF) {
  int f = blockIdx.x;
  int lane = threadIdx.x;
  int wn = f & 7, kk = (f >> 3) % 12, ks = f / 96;
  int n = ks * 128 + wn * 16 + (lane & 15);
  int k = kk * 32 + (lane >> 4) * 8;
  unsigned short* dst = WF + ((size_t)f * 64 + lane) * 8;
#pragma unroll
  for (int j = 0; j < 8; j++) dst[j] = f2bf(W[(size_t)(k + j) * MLPH + n]);
}

// -------- pack fc2_w [1536][384] into phase-2 MFMA fragment order (1m x 8n waves) --------
__global__ void wfrag2(const float* __restrict__ W, unsigned short* __restrict__ WF) {
  int f = blockIdx.x;
  int lane = threadIdx.x;
  int j = f % 3, wn = (f / 3) & 7, kk = (f / 24) & 3, ks = f / 96;
  int n = wn * 48 + j * 16 + (lane & 15);
  int k = ks * 128 + kk * 32 + (lane >> 4) * 8;
  unsigned short* dst = WF + ((size_t)f * 64 + lane) * 8;
#pragma unroll
  for (int jj = 0; jj < 8; jj++) dst[jj] = f2bf(W[(size_t)(k + jj) * CDIM + n]);
}

// ---------------- fused LN1 + QKV GEMM ----------------
__global__ __launch_bounds__(512) void ln_qkv(
    const float* __restrict__ X, const float* __restrict__ g, const float* __restrict__ b,
    const unsigned short* __restrict__ WQF, const float* __restrict__ BQ,
    __hip_bfloat16* __restrict__ QKV) {
  __shared__ unsigned short Al[64][388];
  int tid = threadIdx.x;
  int m0 = blockIdx.x * 64;
  int wave = tid >> 6, lane = tid & 63;
  int l15 = lane & 15, l4 = lane >> 4;

#pragma unroll
  for (int r8 = 0; r8 < 8; r8++) {
    int row = wave * 8 + r8;
    const float* xr = X + (size_t)(m0 + row) * CDIM;
    float vals[6];
    float s = 0.f;
#pragma unroll
    for (int i = 0; i < 6; i++) { vals[i] = xr[lane + i * 64]; s += vals[i]; }
#pragma unroll
    for (int o = 32; o > 0; o >>= 1) s += __shfl_xor(s, o);
    float mean = s * (1.f / 384.f);
    float vs = 0.f;
#pragma unroll
    for (int i = 0; i < 6; i++) { float d = vals[i] - mean; vs += d * d; }
#pragma unroll
    for (int o = 32; o > 0; o >>= 1) vs += __shfl_xor(vs, o);
    float rs = rsqrtf(vs * (1.f / 384.f) + 1e-5f);
#pragma unroll
    for (int i = 0; i < 6; i++) {
      int c = lane + i * 64;
      Al[row][c] = f2bf((vals[i] - mean) * rs * g[c] + b[c]);
    }
  }
  __syncthreads();

  for (int rd = 0; rd < 9; rd++) {
    int G = rd * 8 + wave;
    f32x4 acc[4] = {};
    const unsigned short* wb = WQF + (size_t)(G * 12) * 512 + lane * 8;
#pragma unroll
    for (int kk = 0; kk < 12; kk++) {
      short8 bf = *(const short8*)(wb + kk * 512);
#pragma unroll
      for (int i = 0; i < 4; i++) {
        short8 af = *(const short8*)&Al[i * 16 + l15][kk * 32 + l4 * 8];
        acc[i] = __builtin_amdgcn_mfma_f32_16x16x32_bf16(af, bf, acc[i], 0, 0, 0);
      }
    }
    int n = G * 16 + l15;
    float bv = BQ[n];
    __hip_bfloat16* dst = QKV + (size_t)m0 * QKVC + n;
#pragma unroll
    for (int i = 0; i < 4; i++)
#pragma unroll
      for (int r = 0; r < 4; r++)
        dst[(size_t)(i * 16 + l4 * 4 + r) * QKVC] = __float2bfloat16(acc[i][r] + bv);
  }
}

// ---------------- proj + residual: staged-A, one barrier, fragment-packed weights ----------------
// x1 = bf16( awb @ Wp + bp + X ).  Grid M/64, 8 waves; wave owns 48 of 384 out-cols.
__global__ __launch_bounds__(512) void proj_res(
    const __hip_bfloat16* __restrict__ AW, const unsigned short* __restrict__ WPF,
    const float* __restrict__ BP, const float* __restrict__ X,
    __hip_bfloat16* __restrict__ X1) {
  __shared__ unsigned short Al[64][388];
  int tid = threadIdx.x;
  int m0 = blockIdx.x * 64;
  int wave = tid >> 6, lane = tid & 63;
  int l15 = lane & 15, l4 = lane >> 4;

  {  // stage A 64x384 bf16 coalesced
#pragma unroll
    for (int i = 0; i < 6; i++) {
      int u = tid + i * 512;
      int r = u / 48, col = (u % 48) * 8;
      *(uint4*)&Al[r][col] =
          *(const uint4*)((const unsigned short*)AW + (size_t)(m0 + r) * 384 + col);
    }
  }
  __syncthreads();

  f32x4 acc[4][3] = {};
#pragma unroll
  for (int kk = 0; kk < 12; kk++) {
    short8 af[4];
#pragma unroll
    for (int i = 0; i < 4; i++)
      af[i] = *(const short8*)&Al[i * 16 + l15][kk * 32 + l4 * 8];
#pragma unroll
    for (int j = 0; j < 3; j++) {
      int G = wave * 3 + j;
      short8 bf = *(const short8*)(WPF + (size_t)(G * 12 + kk) * 512 + lane * 8);
#pragma unroll
      for (int i = 0; i < 4; i++)
        acc[i][j] = __builtin_amdgcn_mfma_f32_16x16x32_bf16(af[i], bf, acc[i][j], 0, 0, 0);
    }
  }
#pragma unroll
  for (int j = 0; j < 3; j++) {
    int n = (wave * 3 + j) * 16 + l15;
    float bv = BP[n];
#pragma unroll
    for (int i = 0; i < 4; i++)
#pragma unroll
      for (int r = 0; r < 4; r++) {
        int m = m0 + i * 16 + l4 * 4 + r;
        X1[(size_t)m * 384 + n] =
            __float2bfloat16(acc[i][j][r] + bv + X[(size_t)m * 384 + n]);
      }
  }
}

// ---------------- fused MLP (R10 best): 8 waves 1m x 8n, BM=64; X2 residual bf16 ----------------
__global__ __launch_bounds__(512, 4) void mlp_fused(
    const __hip_bfloat16* __restrict__ XN, const unsigned short* __restrict__ W1F,
    const float* __restrict__ B1, const unsigned short* __restrict__ W2F,
    const float* __restrict__ B2, const __hip_bfloat16* __restrict__ X2,
    float* __restrict__ OUT) {
  __shared__ unsigned short XNl[64][388];
  __shared__ unsigned short Hl[64][132];
  int tid = threadIdx.x;
  int m0 = blockIdx.x * 64;
  int wave = tid >> 6, lane = tid & 63;
  int wn = wave;
  int l15 = lane & 15, l4 = lane >> 4;

  {
#pragma unroll
    for (int i = 0; i < 6; i++) {
      int u = tid + i * 512;
      int r = u / 48, col = (u % 48) * 8;
      *(uint4*)&XNl[r][col] =
          *(const uint4*)((const unsigned short*)XN + (size_t)(m0 + r) * 384 + col);
    }
  }

  f32x4 acc[4][3] = {};
  __syncthreads();

  for (int ks = 0; ks < 12; ks++) {
    f32x4 hacc[4] = {};
    const unsigned short* w1fb = W1F + ((size_t)(ks * 96 + wn)) * 512 + lane * 8;
#pragma unroll
    for (int kk = 0; kk < 12; kk++) {
      short8 bf0 = *(const short8*)(w1fb + kk * 4096);
#pragma unroll
      for (int i = 0; i < 4; i++) {
        short8 af = *(const short8*)&XNl[i * 16 + l15][kk * 32 + l4 * 8];
        hacc[i] = __builtin_amdgcn_mfma_f32_16x16x32_bf16(af, bf0, hacc[i], 0, 0, 0);
      }
    }
    float b1v = B1[ks * 128 + wn * 16 + l15];
    __syncthreads();
#pragma unroll
    for (int i = 0; i < 4; i++)
#pragma unroll
      for (int r = 0; r < 4; r++) {
        float c = hacc[i][r] + b1v;
        Hl[i * 16 + l4 * 4 + r][wn * 16 + l15] = f2bf(gelu_f(c));
      }
    __syncthreads();
    const unsigned short* w2fb = W2F + ((size_t)(ks * 96 + wn * 3)) * 512 + lane * 8;
#pragma unroll
    for (int kk = 0; kk < 4; kk++) {
      short8 af2[4];
#pragma unroll
      for (int i = 0; i < 4; i++)
        af2[i] = *(const short8*)&Hl[i * 16 + l15][kk * 32 + l4 * 8];
#pragma unroll
      for (int j = 0; j < 3; j++) {
        short8 bf2 = *(const short8*)(w2fb + kk * 12288 + j * 512);
#pragma unroll
        for (int i = 0; i < 4; i++)
          acc[i][j] = __builtin_amdgcn_mfma_f32_16x16x32_bf16(af2[i], bf2, acc[i][j], 0, 0, 0);
      }
    }
  }
#pragma unroll
  for (int j = 0; j < 3; j++) {
    int n = wn * 48 + j * 16 + l15;
    float bv = B2[n];
#pragma unroll
    for (int i = 0; i < 4; i++)
#pragma unroll
      for (int r = 0; r < 4; r++) {
        int m = m0 + i * 16 + l4 * 4 + r;
        OUT[(size_t)m * 384 + n] =
            acc[i][j][r] + bv + __bfloat162float(X2[(size_t)m * 384 + n]);
      }
  }
}

// ---------------- MFMA window attention: 1 wave per (window, head) ----------------
__global__ __launch_bounds__(64) void attn_mfma(
    const __hip_bfloat16* __restrict__ qkv, const __hip_bfloat16* __restrict__ qkv_pad,
    const float* __restrict__ Bexp, __hip_bfloat16* __restrict__ aw) {
  int h = blockIdx.x % NHEAD;
  int w = blockIdx.x / NHEAD;
  int b = w / 25, wi = w % 25;
  int wh = wi / 5, wv = wi % 5;

  __shared__ unsigned short Q[64][40];
  __shared__ unsigned short K[64][40];
  __shared__ unsigned short Vt[32][72];
  __shared__ unsigned short P[64][72];

  int lane = threadIdx.x;
  int l15 = lane & 15, l4 = lane >> 4;

  {
    int t = lane;
    uint4 z = {0, 0, 0, 0};
    uint4 qv[4], kv[4];
    union { uint4 u[4]; unsigned short s[32]; } vu;
    bool use = t < 49;
    const unsigned short* src = (const unsigned short*)qkv_pad + h * 96;
    if (use) {
      int hh = wh * 7 + t / 7, ww = wv * 7 + t % 7;
      if (hh < 32 && ww < 32)
        src = (const unsigned short*)qkv + (size_t)(b * 1024 + hh * 32 + ww) * QKVC + h * 96;
    }
#pragma unroll
    for (int c = 0; c < 4; c++) {
      qv[c]   = use ? *(const uint4*)(src + c * 8)      : z;
      kv[c]   = use ? *(const uint4*)(src + 32 + c * 8) : z;
      vu.u[c] = use ? *(const uint4*)(src + 64 + c * 8) : z;
    }
#pragma unroll
    for (int c = 0; c < 4; c++) {
      *(uint4*)&Q[t][c * 8] = qv[c];
      *(uint4*)&K[t][c * 8] = kv[c];
    }
#pragma unroll
    for (int d = 0; d < 32; d++) Vt[d][t] = vu.s[d];
  }
  __syncthreads();

  f32x4 acc[4][4] = {};
  {
    short8 aq[4], bk[4];
#pragma unroll
    for (int i = 0; i < 4; i++) aq[i] = *(const short8*)&Q[i * 16 + l15][l4 * 8];
#pragma unroll
    for (int j = 0; j < 4; j++) bk[j] = *(const short8*)&K[j * 16 + l15][l4 * 8];
#pragma unroll
    for (int i = 0; i < 4; i++)
#pragma unroll
      for (int j = 0; j < 4; j++)
        acc[i][j] = __builtin_amdgcn_mfma_f32_16x16x32_bf16(aq[i], bk[j], acc[i][j], 0, 0, 0);
  }

  const float* Bh = Bexp + h * 4096;
  float rinv_[4][4];
#pragma unroll
  for (int i = 0; i < 4; i++) {
    float s[4][4];
#pragma unroll
    for (int j = 0; j < 4; j++)
#pragma unroll
      for (int r = 0; r < 4; r++) {
        int n = i * 16 + l4 * 4 + r, m = j * 16 + l15;
        s[j][r] = acc[i][j][r] * SCALE + Bh[n * 64 + m];
      }
#pragma unroll
    for (int r = 0; r < 4; r++) {
      float mx = fmaxf(fmaxf(s[0][r], s[1][r]), fmaxf(s[2][r], s[3][r]));
#pragma unroll
      for (int o = 1; o < 16; o <<= 1) mx = fmaxf(mx, __shfl_xor(mx, o));
      float p[4], sm = 0.f;
#pragma unroll
      for (int j = 0; j < 4; j++) { p[j] = __expf(s[j][r] - mx); sm += p[j]; }
#pragma unroll
      for (int o = 1; o < 16; o <<= 1) sm += __shfl_xor(sm, o);
      rinv_[i][r] = 1.f / sm;
      int n = i * 16 + l4 * 4 + r;
#pragma unroll
      for (int j = 0; j < 4; j++) P[n][j * 16 + l15] = f2bf(p[j]);
    }
  }
  __syncthreads();

  f32x4 o[4][2] = {};
#pragma unroll
  for (int ks = 0; ks < 2; ks++) {
    short8 pa[4], vb[2];
#pragma unroll
    for (int i = 0; i < 4; i++) pa[i] = *(const short8*)&P[i * 16 + l15][ks * 32 + l4 * 8];
#pragma unroll
    for (int j = 0; j < 2; j++) vb[j] = *(const short8*)&Vt[j * 16 + l15][ks * 32 + l4 * 8];
#pragma unroll
    for (int i = 0; i < 4; i++)
#pragma unroll
      for (int j = 0; j < 2; j++)
        o[i][j] = __builtin_amdgcn_mfma_f32_16x16x32_bf16(pa[i], vb[j], o[i][j], 0, 0, 0);
  }

#pragma unroll
  for (int i = 0; i < 4; i++)
#pragma unroll
    for (int r = 0; r < 4; r++) {
      int n = i * 16 + l4 * 4 + r;
      if (n < 49) {
        int hh = wh * 7 + n / 7, ww = wv * 7 + n % 7;
        if (hh < 32 && ww < 32) {
          __hip_bfloat16* dst = aw + (size_t)(b * 1024 + hh * 32 + ww) * CDIM + h * 32;
          float ri = rinv_[i][r];
#pragma unroll
          for (int j = 0; j < 2; j++)
            dst[j * 16 + l15] = __float2bfloat16(o[i][j][r] * ri);
        }
      }
    }
}

// ------- fused depthwise 3x3 conv + BN + LN2 (x1 bf16 in, x2 bf16 out) -------
__global__ __launch_bounds__(384) void conv_bn_ln_kernel(
    const __hip_bfloat16* __restrict__ X, const float* __restrict__ W9,
    const float* __restrict__ g, const float* __restrict__ bb,
    const float* __restrict__ mm, const float* __restrict__ vv,
    const float* __restrict__ lg, const float* __restrict__ lb,
    __hip_bfloat16* __restrict__ X2, __hip_bfloat16* __restrict__ XN) {
  int nwg = gridDim.x;
  int id = blockIdx.x;
  int nid = (id & 7) * (nwg >> 3) + (id >> 3);
  int yh = nid & 1;
  int x = (nid >> 1) & 31;
  int b = nid >> 6;
  int c = threadIdx.x;

  float w[9];
#pragma unroll
  for (int i = 0; i < 9; i++) w[i] = W9[c * 9 + i];
  float bnsc = rsqrtf(vv[c] + 1e-5f) * g[c];
  float bnsh = bb[c] - mm[c] * bnsc;
  float lgc = lg[c], lbc = lb[c];

  bool xm = x > 0, xp = x < 31;
  const __hip_bfloat16* colbase = X + ((size_t)(b * 1024 + x)) * CDIM + c;

  __shared__ float part[2][6][2];
  int wv = threadIdx.x >> 6, ln = threadIdx.x & 63;

  float w0[3], w1[3], w2[3];
  int y0 = yh * 16;
  if (y0 == 0) {
    w0[0] = w0[1] = w0[2] = 0.f;
  } else {
    const __hip_bfloat16* p = colbase + (size_t)(y0 - 1) * 32 * CDIM;
    w0[0] = xm ? __bfloat162float(p[-CDIM]) : 0.f;
    w0[1] = __bfloat162float(p[0]);
    w0[2] = xp ? __bfloat162float(p[CDIM]) : 0.f;
  }
  {
    const __hip_bfloat16* p = colbase + (size_t)y0 * 32 * CDIM;
    w1[0] = xm ? __bfloat162float(p[-CDIM]) : 0.f;
    w1[1] = __bfloat162float(p[0]);
    w1[2] = xp ? __bfloat162float(p[CDIM]) : 0.f;
  }

  for (int y = y0; y < y0 + 16; y++) {
    if (y + 1 < 32) {
      const __hip_bfloat16* p = colbase + (size_t)(y + 1) * 32 * CDIM;
      w2[0] = xm ? __bfloat162float(p[-CDIM]) : 0.f;
      w2[1] = __bfloat162float(p[0]);
      w2[2] = xp ? __bfloat162float(p[CDIM]) : 0.f;
    } else {
      w2[0] = w2[1] = w2[2] = 0.f;
    }
    float acc = w0[0] * w[0] + w0[1] * w[1] + w0[2] * w[2]
              + w1[0] * w[3] + w1[1] * w[4] + w1[2] * w[5]
              + w2[0] * w[6] + w2[1] * w[7] + w2[2] * w[8];
    float r = acc * bnsc + bnsh;
    size_t tok = (size_t)(b * 1024 + y * 32 + x);
    X2[tok * CDIM + c] = __float2bfloat16(r);

    float s1 = r, s2 = r * r;
#pragma unroll
    for (int o = 32; o > 0; o >>= 1) { s1 += __shfl_xor(s1, o); s2 += __shfl_xor(s2, o); }
    int pb = y & 1;
    if (ln == 0) { part[pb][wv][0] = s1; part[pb][wv][1] = s2; }
    __syncthreads();
    float ts1 = 0.f, ts2 = 0.f;
#pragma unroll
    for (int i = 0; i < 6; i++) { ts1 += part[pb][i][0]; ts2 += part[pb][i][1]; }
    float mean = ts1 * (1.f / 384.f);
    float var = ts2 * (1.f / 384.f) - mean * mean;
    float rstd = rsqrtf(var + 1e-5f);
    XN[tok * CDIM + c] = __float2bfloat16((r - mean) * rstd * lgc + lbc);

    w0[0] = w1[0]; w0[1] = w1[1]; w0[2] = w1[2];
    w1[0] = w2[0]; w1[1] = w2[1]; w1[2] = w2[2];
  }
}

extern "C" void kernel_launch(void* const* d_in, const int* in_sizes, int n_in,
                              void* d_out, int out_size, void* d_ws, size_t ws_size,
                              hipStream_t stream) {
  const float* x      = (const float*)d_in[0];
  const float* ln1_g  = (const float*)d_in[1];
  const float* ln1_b  = (const float*)d_in[2];
  const float* qkv_w  = (const float*)d_in[3];
  const float* qkv_b  = (const float*)d_in[4];
  const float* proj_w = (const float*)d_in[5];
  const float* proj_b = (const float*)d_in[6];
  const float* att_b  = (const float*)d_in[7];
  const float* conv_w = (const float*)d_in[8];
  const float* bn_g   = (const float*)d_in[9];
  const float* bn_b   = (const float*)d_in[10];
  const float* bn_m   = (const float*)d_in[11];
  const float* bn_v   = (const float*)d_in[12];
  const float* ln2_g  = (const float*)d_in[13];
  const float* ln2_b  = (const float*)d_in[14];
  const float* fc1_w  = (const float*)d_in[15];
  const float* fc1_b  = (const float*)d_in[16];
  const float* fc2_w  = (const float*)d_in[17];
  const float* fc2_b  = (const float*)d_in[18];
  const int* bias_idxs = (const int*)d_in[19];
  int n_off = in_sizes[7] / NHEAD;
  float* out = (float*)d_out;

  char* ws = (char*)d_ws;
  size_t off = 0;
  __hip_bfloat16* qkv_pad = (__hip_bfloat16*)(ws + off); off += QKVC * 2;
  off = (off + 255) & ~(size_t)255;
  float* Bexp = (float*)(ws + off); off += (size_t)NHEAD * 4096 * 4;
  unsigned short* wqf = (unsigned short*)(ws + off); off += (size_t)QKVC * CDIM * 2;
  unsigned short* wpf = (unsigned short*)(ws + off); off += (size_t)CDIM * CDIM * 2;
  unsigned short* w1f = (unsigned short*)(ws + off); off += (size_t)MLPH * CDIM * 2;
  unsigned short* w2f = (unsigned short*)(ws + off); off += (size_t)CDIM * MLPH * 2;
  size_t HDR = (off + 255) & ~(size_t)255;

  // per-token chunk scratch (x1 aliases qkv, both bf16):
  // qkv/x1 (2304) + xn bf16(768) + awb bf16(768) + x2 bf16(768) = 4608 B
  const size_t PER_TOK = 4608;
  int Bc = 64;
  while (Bc > 1 && HDR + (size_t)Bc * 1024 * PER_TOK > ws_size) Bc >>= 1;
  size_t Tc = (size_t)Bc * 1024;

  off = HDR;
  __hip_bfloat16* xn = (__hip_bfloat16*)(ws + off); off += Tc * CDIM * 2;
  __hip_bfloat16* qkv = (__hip_bfloat16*)(ws + off); off += Tc * QKVC * 2;
  __hip_bfloat16* x1 = qkv;  // alias: qkv dead after attn_mfma
  __hip_bfloat16* awb = (__hip_bfloat16*)(ws + off); off += Tc * CDIM * 2;
  __hip_bfloat16* x2 = (__hip_bfloat16*)(ws + off); off += Tc * CDIM * 2;

  pad_qkv_kernel<<<dim3(5), dim3(256), 0, stream>>>(ln1_b, qkv_w, qkv_b, qkv_pad);
  expand_bias<<<dim3(NHEAD), dim3(256), 0, stream>>>(att_b, bias_idxs, Bexp, n_off);
  wfragq<<<dim3(864), dim3(64), 0, stream>>>(qkv_w, wqf);
  wfragp<<<dim3(288), dim3(64), 0, stream>>>(proj_w, wpf);
  wfrag1<<<dim3(1152), dim3(64), 0, stream>>>(fc1_w, w1f);
  wfrag2<<<dim3(1152), dim3(64), 0, stream>>>(fc2_w, w2f);

  for (int b0 = 0; b0 < 64; b0 += Bc) {
    const float* xa = x + (size_t)b0 * 1024 * CDIM;
    float* outa = out + (size_t)b0 * 1024 * CDIM;
    int M = (int)Tc;

    ln_qkv<<<dim3(M / 64), dim3(512), 0, stream>>>(xa, ln1_g, ln1_b, wqf, qkv_b, qkv);
    attn_mfma<<<dim3(Bc * 25 * NHEAD), dim3(64), 0, stream>>>(qkv, qkv_pad, Bexp, awb);
    proj_res<<<dim3(M / 64), dim3(512), 0, stream>>>(awb, wpf, proj_b, xa, x1);
    conv_bn_ln_kernel<<<dim3(Bc * 64), dim3(384), 0, stream>>>(
        x1, conv_w, bn_g, bn_b, bn_m, bn_v, ln2_g, ln2_b, x2, xn);
    mlp_fused<<<dim3(M / 64), dim3(512), 0, stream>>>(
        xn, w1f, fc1_b, w2f, fc2_b, x2, outa);
  }
}